// Round 6
// baseline (1057.652 us; speedup 1.0000x reference)
//
#include <hip/hip_runtime.h>
#include <hip/hip_bf16.h>
#include <stdint.h>

#define E_DIM 1280
#define F_DIM 5120
#define T_DIM 16384
#define B_SZ  16
#define S_LEN 1024
#define NH    20

typedef int v4i __attribute__((ext_vector_type(4)));
typedef __attribute__((ext_vector_type(8))) short v8s;
typedef __attribute__((ext_vector_type(4))) float v4f;

// ---------- helpers ----------
__device__ __forceinline__ float wred_sum(float v) {
#pragma unroll
  for (int m = 32; m > 0; m >>= 1) v += __shfl_xor(v, m, 64);
  return v;
}
__device__ __forceinline__ float wred_max(float v) {
#pragma unroll
  for (int m = 32; m > 0; m >>= 1) v = fmaxf(v, __shfl_xor(v, m, 64));
  return v;
}
__device__ __forceinline__ void gload_lds16(const void* g, void* l) {
  __builtin_amdgcn_global_load_lds((const __attribute__((address_space(1))) void*)g,
                                   (__attribute__((address_space(3))) void*)l, 16, 0, 0);
}

// ---------- per-output-channel weight quant ----------
__global__ __launch_bounds__(256) void wquant_kernel(
    const float* __restrict__ W, int8_t* __restrict__ qw, float* __restrict__ sw, int K) {
  __shared__ float red[4];
  const int row = blockIdx.x;
  const int tid = threadIdx.x;
  const float* wr = W + (size_t)row * K;
  float amax = 0.f;
  for (int c = tid; c < K; c += 256) amax = fmaxf(amax, fabsf(wr[c]));
  amax = wred_max(amax);
  if ((tid & 63) == 0) red[tid >> 6] = amax;
  __syncthreads();
  amax = fmaxf(fmaxf(red[0], red[1]), fmaxf(red[2], red[3]));
  float sc = amax * (1.0f / 127.0f);
  if (tid == 0) sw[row] = sc;
  for (int c = tid; c < K; c += 256) {
    float qv = rintf(wr[c] / sc);
    qw[(size_t)row * K + c] = (int8_t)qv;
  }
}

// ---------- RMSNorm(+bias) + per-token quant (E=1280) ----------
__global__ __launch_bounds__(256) void rms_quant_kernel(
    const float* __restrict__ x, const float* __restrict__ w, const float* __restrict__ b,
    int8_t* __restrict__ q, float* __restrict__ s) {
  __shared__ float red[4];
  const int row = blockIdx.x;
  const int tid = threadIdx.x;
  const float* xr = x + (size_t)row * E_DIM;
  float vals[5];
  float ss = 0.f;
#pragma unroll
  for (int i = 0; i < 5; ++i) {
    float v = xr[tid + i * 256];
    vals[i] = v; ss += v * v;
  }
  ss = wred_sum(ss);
  if ((tid & 63) == 0) red[tid >> 6] = ss;
  __syncthreads();
  ss = red[0] + red[1] + red[2] + red[3];
  float rstd = rsqrtf(ss * (1.0f / E_DIM) + 1e-6f);
  float y[5]; float amax = 0.f;
#pragma unroll
  for (int i = 0; i < 5; ++i) {
    int c = tid + i * 256;
    float v = vals[i] * rstd * w[c] + b[c];
    y[i] = v;
    amax = fmaxf(amax, fabsf(v));
  }
  amax = wred_max(amax);
  __syncthreads();
  if ((tid & 63) == 0) red[tid >> 6] = amax;
  __syncthreads();
  amax = fmaxf(fmaxf(red[0], red[1]), fmaxf(red[2], red[3]));
  float sc = amax * (1.0f / 127.0f);
  if (tid == 0) s[row] = sc;
#pragma unroll
  for (int i = 0; i < 5; ++i) {
    int c = tid + i * 256;
    float qv = rintf(y[i] / sc);
    qv = fminf(fmaxf(qv, -127.f), 127.f);
    q[(size_t)row * E_DIM + c] = (int8_t)qv;
  }
}

// ---------- per-token quant (E=1280, bf16 in) ----------
__global__ __launch_bounds__(256) void row_quant_bf_kernel(
    const __hip_bfloat16* __restrict__ x, int8_t* __restrict__ q, float* __restrict__ s) {
  __shared__ float red[4];
  const int row = blockIdx.x;
  const int tid = threadIdx.x;
  const __hip_bfloat16* xr = x + (size_t)row * E_DIM;
  float vals[5]; float amax = 0.f;
#pragma unroll
  for (int i = 0; i < 5; ++i) {
    float v = __bfloat162float(xr[tid + i * 256]);
    vals[i] = v;
    amax = fmaxf(amax, fabsf(v));
  }
  amax = wred_max(amax);
  if ((tid & 63) == 0) red[tid >> 6] = amax;
  __syncthreads();
  amax = fmaxf(fmaxf(red[0], red[1]), fmaxf(red[2], red[3]));
  float sc = amax * (1.0f / 127.0f);
  if (tid == 0) s[row] = sc;
#pragma unroll
  for (int i = 0; i < 5; ++i) {
    int c = tid + i * 256;
    float qv = rintf(vals[i] / sc);
    qv = fminf(fmaxf(qv, -127.f), 127.f);
    q[(size_t)row * E_DIM + c] = (int8_t)qv;
  }
}

// ---------- exact GELU + per-token quant (F=5120, bf16 in, int8 in-place) ----------
__global__ __launch_bounds__(256) void gelu_quant_kernel(
    const __hip_bfloat16* __restrict__ f1, int8_t* __restrict__ q, float* __restrict__ s) {
  __shared__ float red[4];
  const int row = blockIdx.x;
  const int tid = threadIdx.x;
  const __hip_bfloat16* xr = f1 + (size_t)row * F_DIM;
  float g[20]; float amax = 0.f;
#pragma unroll
  for (int i = 0; i < 20; ++i) {
    float v = __bfloat162float(xr[tid + i * 256]);
    float gv = 0.5f * v * (1.0f + erff(v * 0.70710678118654752440f));
    g[i] = gv;
    amax = fmaxf(amax, fabsf(gv));
  }
  amax = wred_max(amax);
  if ((tid & 63) == 0) red[tid >> 6] = amax;
  __syncthreads();
  amax = fmaxf(fmaxf(red[0], red[1]), fmaxf(red[2], red[3]));
  float sc = amax * (1.0f / 127.0f);
  if (tid == 0) s[row] = sc;
  int8_t* qr = q + (size_t)row * (2 * F_DIM);   // strided in-place rows
#pragma unroll
  for (int i = 0; i < 20; ++i) {
    int c = tid + i * 256;
    float qv = rintf(g[i] / sc);
    qv = fminf(fmaxf(qv, -127.f), 127.f);
    qr[c] = (int8_t)qv;
  }
}

// ============================================================================
// int8 GEMM, 256x256 tile, 8 waves, ring-of-4 K-tiles (BK=64), 16x16x64 MFMA.
// (conflict-free frag-read pattern; measured 0 LDS bank conflicts)
// ============================================================================
template <int MODE>
__global__ __launch_bounds__(512, 2) void gemm256_i8(
    const int8_t* __restrict__ A, const int8_t* __restrict__ B,
    const float* __restrict__ sx, const float* __restrict__ sw,
    const float* __restrict__ bias, const float* __restrict__ resid,
    void* __restrict__ outp, int M, int N, int K, int lda) {
  __shared__ __align__(16) int8_t As[2][2][256 * 64];
  __shared__ __align__(16) int8_t Bs[2][2][256 * 64];

  const int tid = threadIdx.x;
  const int lane = tid & 63;
  const int wave = tid >> 6;
  const int wm = wave >> 2;                       // 0..1  (M half)
  const int wn = wave & 3;                        // 0..3  (N quarter)
  const int l16 = lane & 15;
  const int quad = lane >> 4;
  const int choff = (quad ^ ((l16 >> 1) & 3)) << 4;   // read-side swizzled chunk

  // XCD-aware bijective swizzle (all grids divisible by 8)
  const int nwg = gridDim.x;
  const int ntn = N >> 8;
  const int u = (blockIdx.x & 7) * (nwg >> 3) + (blockIdx.x >> 3);
  const int tm = u / ntn, tn = u % ntn;
  const int m0 = tm << 8, n0 = tn << 8;

  const int8_t* A_blk = A + (size_t)m0 * lda;
  const int8_t* B_blk = B + (size_t)n0 * K;

  const int r0 = tid >> 2;                              // staged row (0..127)
  const int sch = ((tid & 3) ^ ((tid >> 3) & 3)) << 4;  // stage-side inv swizzle

#define STAGE_A(KT, DST)                                                         \
  {                                                                              \
    gload_lds16(A_blk + (size_t)r0 * lda + (size_t)(KT)*64 + sch,                \
                (DST) + tid * 16);                                               \
    gload_lds16(A_blk + (size_t)(r0 + 128) * lda + (size_t)(KT)*64 + sch,        \
                (DST) + 8192 + tid * 16);                                        \
  }
#define STAGE_B(KT, DST)                                                         \
  {                                                                              \
    gload_lds16(B_blk + (size_t)r0 * K + (size_t)(KT)*64 + sch,                  \
                (DST) + tid * 16);                                               \
    gload_lds16(B_blk + (size_t)(r0 + 128) * K + (size_t)(KT)*64 + sch,          \
                (DST) + 8192 + tid * 16);                                        \
  }

  v4i acc[8][4];
#pragma unroll
  for (int i = 0; i < 8; ++i)
#pragma unroll
    for (int j = 0; j < 4; ++j) acc[i][j] = (v4i){0, 0, 0, 0};

  const int nk = K >> 6;          // K-tiles of 64
  const int niter = nk >> 1;      // pairs of K-tiles

  // ---- prologue: stage tiles 0,1 into pair 0; wait tile 0 (oldest 4 of 8) ----
  STAGE_A(0, &As[0][0][0]); STAGE_B(0, &Bs[0][0][0]);
  STAGE_A(1, &As[0][1][0]); STAGE_B(1, &Bs[0][1][0]);
  asm volatile("s_waitcnt vmcnt(4)" ::: "memory");
  asm volatile("s_barrier" ::: "memory");

#pragma unroll 1
  for (int i = 0; i < niter - 1; ++i) {
    const int pr = i & 1;
    const int kt2 = 2 * i + 2;
#pragma unroll
    for (int ph = 0; ph < 4; ++ph) {
      const int tt = ph >> 1;     // tile within pair
      const int qm = ph & 1;      // M half of fragments
      const int8_t* At = &As[pr][tt][0];
      const int8_t* Bt = &Bs[pr][tt][0];
      v4i af[4], bf[4];
#pragma unroll
      for (int ii = 0; ii < 4; ++ii)
        af[ii] = *(const v4i*)(At + (wm * 128 + qm * 64 + ii * 16 + l16) * 64 + choff);
#pragma unroll
      for (int jj = 0; jj < 4; ++jj)
        bf[jj] = *(const v4i*)(Bt + (wn * 64 + jj * 16 + l16) * 64 + choff);
      // stage one half-matrix of the next pair's tile (2 loads)
      if (qm == 0) {
        STAGE_A(kt2 + tt, &As[pr ^ 1][tt][0]);
      } else {
        STAGE_B(kt2 + tt, &Bs[pr ^ 1][tt][0]);
      }
      asm volatile("s_barrier" ::: "memory");
      __builtin_amdgcn_s_setprio(1);
#pragma unroll
      for (int ii = 0; ii < 4; ++ii)
#pragma unroll
        for (int jj = 0; jj < 4; ++jj)
          acc[qm * 4 + ii][jj] = __builtin_amdgcn_mfma_i32_16x16x64_i8(
              af[ii], bf[jj], acc[qm * 4 + ii][jj], 0, 0, 0);
      __builtin_amdgcn_s_setprio(0);
      if (qm == 1) asm volatile("s_waitcnt vmcnt(4)" ::: "memory");
      asm volatile("s_barrier" ::: "memory");
    }
  }

  // ---- peeled final pair: no staging; drain remaining tile at phase 1 ----
  {
    const int pr = (niter - 1) & 1;
#pragma unroll
    for (int ph = 0; ph < 4; ++ph) {
      const int tt = ph >> 1;
      const int qm = ph & 1;
      const int8_t* At = &As[pr][tt][0];
      const int8_t* Bt = &Bs[pr][tt][0];
      v4i af[4], bf[4];
#pragma unroll
      for (int ii = 0; ii < 4; ++ii)
        af[ii] = *(const v4i*)(At + (wm * 128 + qm * 64 + ii * 16 + l16) * 64 + choff);
#pragma unroll
      for (int jj = 0; jj < 4; ++jj)
        bf[jj] = *(const v4i*)(Bt + (wn * 64 + jj * 16 + l16) * 64 + choff);
      asm volatile("s_barrier" ::: "memory");
      __builtin_amdgcn_s_setprio(1);
#pragma unroll
      for (int ii = 0; ii < 4; ++ii)
#pragma unroll
        for (int jj = 0; jj < 4; ++jj)
          acc[qm * 4 + ii][jj] = __builtin_amdgcn_mfma_i32_16x16x64_i8(
              af[ii], bf[jj], acc[qm * 4 + ii][jj], 0, 0, 0);
      __builtin_amdgcn_s_setprio(0);
      if (ph == 1) asm volatile("s_waitcnt vmcnt(0)" ::: "memory");
      asm volatile("s_barrier" ::: "memory");
    }
  }
#undef STAGE_A
#undef STAGE_B

  // ---- epilogue ----
  float swv[4], bv[4];
#pragma unroll
  for (int jj = 0; jj < 4; ++jj) {
    int n = n0 + wn * 64 + jj * 16 + l16;
    swv[jj] = sw[n];
    bv[jj] = bias[n];
  }
#pragma unroll
  for (int mf = 0; mf < 8; ++mf) {
#pragma unroll
    for (int r = 0; r < 4; ++r) {
      int m = m0 + wm * 128 + mf * 16 + quad * 4 + r;
      float sxm = sx[m];
#pragma unroll
      for (int jj = 0; jj < 4; ++jj) {
        int n = n0 + wn * 64 + jj * 16 + l16;
        float v = (float)acc[mf][jj][r] * (sxm * swv[jj]) + bv[jj];
        if constexpr (MODE == 0) {
          ((__hip_bfloat16*)outp)[(size_t)m * N + n] = __float2bfloat16(v);
        } else {
          ((float*)outp)[(size_t)m * N + n] = v + resid[(size_t)m * N + n];
        }
      }
    }
  }
}

// ============================================================================
// int8 GEMM, 128x128 tile, 4 waves, ring-of-4 K-tiles, 16x16x64 MFMA.
// 64 KiB LDS -> 2 blocks/CU; grid 1280 = 5 exact dispatch rounds.
// ============================================================================
template <int MODE>
__global__ __launch_bounds__(256, 2) void gemm128_i8(
    const int8_t* __restrict__ A, const int8_t* __restrict__ B,
    const float* __restrict__ sx, const float* __restrict__ sw,
    const float* __restrict__ bias, const float* __restrict__ resid,
    void* __restrict__ outp, int M, int N, int K, int lda) {
  __shared__ __align__(16) int8_t As[4][128 * 64];
  __shared__ __align__(16) int8_t Bs[4][128 * 64];

  const int tid = threadIdx.x;
  const int lane = tid & 63;
  const int wave = tid >> 6;
  const int wm = wave >> 1;                       // 0..1
  const int wn = wave & 1;                        // 0..1
  const int l16 = lane & 15;
  const int quad = lane >> 4;
  const int choff = (quad ^ ((l16 >> 1) & 3)) << 4;   // conflict-free pattern

  // XCD-aware bijective swizzle (grid divisible by 8)
  const int nwg = gridDim.x;
  const int ntn = N >> 7;
  const int u = (blockIdx.x & 7) * (nwg >> 3) + (blockIdx.x >> 3);
  const int tm = u / ntn, tn = u % ntn;
  const int m0 = tm << 7, n0 = tn << 7;

  const int8_t* A_blk = A + (size_t)m0 * lda;
  const int8_t* B_blk = B + (size_t)n0 * K;

  const int r0 = tid >> 2;                              // 0..63
  const int sch = ((tid & 3) ^ ((tid >> 3) & 3)) << 4;

#define STAGE_A(KT, SLOT)                                                        \
  {                                                                              \
    gload_lds16(A_blk + (size_t)r0 * lda + (size_t)(KT)*64 + sch,                \
                &As[SLOT][tid * 16]);                                            \
    gload_lds16(A_blk + (size_t)(r0 + 64) * lda + (size_t)(KT)*64 + sch,         \
                &As[SLOT][4096 + tid * 16]);                                     \
  }
#define STAGE_B(KT, SLOT)                                                        \
  {                                                                              \
    gload_lds16(B_blk + (size_t)r0 * K + (size_t)(KT)*64 + sch,                  \
                &Bs[SLOT][tid * 16]);                                            \
    gload_lds16(B_blk + (size_t)(r0 + 64) * K + (size_t)(KT)*64 + sch,           \
                &Bs[SLOT][4096 + tid * 16]);                                     \
  }

#define KTILE(SLOT, STAGE_STMT, WAIT_STMT)                                       \
  {                                                                              \
    const int8_t* At = &As[SLOT][0];                                             \
    const int8_t* Bt = &Bs[SLOT][0];                                             \
    v4i af[4], bf[4];                                                            \
    _Pragma("unroll") for (int ii = 0; ii < 4; ++ii)                             \
        af[ii] = *(const v4i*)(At + (wm * 64 + ii * 16 + l16) * 64 + choff);     \
    _Pragma("unroll") for (int jj = 0; jj < 4; ++jj)                             \
        bf[jj] = *(const v4i*)(Bt + (wn * 64 + jj * 16 + l16) * 64 + choff);     \
    STAGE_STMT;                                                                  \
    asm volatile("s_barrier" ::: "memory");                                      \
    __builtin_amdgcn_s_setprio(1);                                               \
    _Pragma("unroll") for (int ii = 0; ii < 4; ++ii)                             \
        _Pragma("unroll") for (int jj = 0; jj < 4; ++jj)                         \
            acc[ii][jj] = __builtin_amdgcn_mfma_i32_16x16x64_i8(                 \
                af[ii], bf[jj], acc[ii][jj], 0, 0, 0);                           \
    __builtin_amdgcn_s_setprio(0);                                               \
    WAIT_STMT;                                                                   \
    asm volatile("s_barrier" ::: "memory");                                      \
  }

  v4i acc[4][4];
#pragma unroll
  for (int i = 0; i < 4; ++i)
#pragma unroll
    for (int j = 0; j < 4; ++j) acc[i][j] = (v4i){0, 0, 0, 0};

  const int nk = K >> 6;          // >= 4 for all call sites

  // ---- prologue: stage tiles 0,1,2 (12 loads); wait tile 0 (oldest 4) ----
  STAGE_A(0, 0); STAGE_B(0, 0);
  STAGE_A(1, 1); STAGE_B(1, 1);
  STAGE_A(2, 2); STAGE_B(2, 2);
  asm volatile("s_waitcnt vmcnt(8)" ::: "memory");
  asm volatile("s_barrier" ::: "memory");

#pragma unroll 1
  for (int kt = 0; kt < nk - 3; ++kt) {
    const int sl = kt & 3;
    const int s3 = (kt + 3) & 3;
    KTILE(sl, { STAGE_A(kt + 3, s3); STAGE_B(kt + 3, s3); },
          asm volatile("s_waitcnt vmcnt(8)" ::: "memory"));
  }
  // ---- peel last 3 K-tiles (no staging; drain 8 -> 4 -> 0) ----
  KTILE((nk - 3) & 3, ((void)0), asm volatile("s_waitcnt vmcnt(4)" ::: "memory"));
  KTILE((nk - 2) & 3, ((void)0), asm volatile("s_waitcnt vmcnt(0)" ::: "memory"));
  KTILE((nk - 1) & 3, ((void)0), ((void)0));
#undef KTILE
#undef STAGE_A
#undef STAGE_B

  // ---- epilogue (16x16 C layout: col=lane&15, row=quad*4+r) ----
  float swv[4], bv[4];
#pragma unroll
  for (int jj = 0; jj < 4; ++jj) {
    int n = n0 + wn * 64 + jj * 16 + l16;
    swv[jj] = sw[n];
    bv[jj] = bias[n];
  }
#pragma unroll
  for (int ii = 0; ii < 4; ++ii) {
#pragma unroll
    for (int r = 0; r < 4; ++r) {
      int m = m0 + wm * 64 + ii * 16 + quad * 4 + r;
      float sxm = sx[m];
#pragma unroll
      for (int jj = 0; jj < 4; ++jj) {
        int n = n0 + wn * 64 + jj * 16 + l16;
        float v = (float)acc[ii][jj][r] * (sxm * swv[jj]) + bv[jj];
        if constexpr (MODE == 0) {
          ((__hip_bfloat16*)outp)[(size_t)m * N + n] = __float2bfloat16(v);
        } else {
          ((float*)outp)[(size_t)m * N + n] = v + resid[(size_t)m * N + n];
        }
      }
    }
  }
}

// ---------- V transpose: Vt[bh][d][k] = V[b,k,h,d] ----------
__global__ __launch_bounds__(256) void vt_kernel(
    const __hip_bfloat16* __restrict__ qkv, __hip_bfloat16* __restrict__ Vt) {
  __shared__ __hip_bfloat16 tile[64][72];
  const int bh = blockIdx.y, kc = blockIdx.x;
  const int b = bh / NH, h = bh % NH;
  const int tid = threadIdx.x;
  const size_t base = ((size_t)b * S_LEN + (size_t)kc * 64) * (3 * E_DIM) + 2 * E_DIM + h * 64;
#pragma unroll
  for (int i = 0; i < 2; ++i) {
    int idx = tid + i * 256;
    int row = idx >> 3, c8 = (idx & 7) * 8;
    *(uint4*)&tile[row][c8] = *(const uint4*)(qkv + base + (size_t)row * (3 * E_DIM) + c8);
  }
  __syncthreads();
#pragma unroll
  for (int i = 0; i < 2; ++i) {
    int idx = tid + i * 256;
    int d = idx >> 3, k8 = (idx & 7) * 8;
    __hip_bfloat16 v[8] __attribute__((aligned(16)));
#pragma unroll
    for (int j = 0; j < 8; ++j) v[j] = tile[k8 + j][d];
    *(uint4*)&Vt[((size_t)bh * 64 + d) * 1024 + (size_t)kc * 64 + k8] = *(uint4*)v;
  }
}

// ---------- flash MFMA attention: 256 thr, 4 waves, 64 q-rows/block ----------
// r3 staging (direct gload_lds, 2 barriers/tile, 3 blocks/CU) + XCD-locality
// grid + exp2 softmax + defer-max + setprio + t-invariant address hoisting.
__global__ __launch_bounds__(256, 3) void attn_flash_kernel(
    const __hip_bfloat16* __restrict__ qkv, const __hip_bfloat16* __restrict__ Vt,
    __hip_bfloat16* __restrict__ attn) {
  constexpr int E3 = 3 * E_DIM;
  __shared__ __align__(16) __hip_bfloat16 Ks[128 * 64];   // [row][8 chunks, ^(row&7)]
  __shared__ __align__(16) __hip_bfloat16 Vs[64 * 128];   // [d][16 chunks, ^(d&15)]
  __shared__ __align__(16) __hip_bfloat16 Ps[4][16 * 128];// per wave [q][16 ch, ^(q)]
  __shared__ float stats[4][16];

  const int tid = threadIdx.x;
  const int lane = tid & 63;
  const int wave = tid >> 6;
  const int l16 = lane & 15;
  const int quad = lane >> 4;
  // XCD-locality 1D grid (5120 wgs): all 16 q-chunks of one (b,h) run
  // back-to-back on one XCD -> K/V stays in that XCD's L2 (FETCH 348->61MB).
  const int wg = (blockIdx.x & 7) * 640 + (blockIdx.x >> 3);
  const int bh = wg >> 4;
  const int b = bh / NH, h = bh % NH;
  const int q0 = (wg & 15) * 64;
  const size_t base_t = (size_t)b * S_LEN;

  // Q B-fragments for this wave's 16 q-rows
  v8s qb0, qb1;
  {
    const __hip_bfloat16* qp =
        qkv + (base_t + q0 + wave * 16 + l16) * (size_t)E3 + h * 64 + quad * 8;
    qb0 = *(const v8s*)qp;
    qb1 = *(const v8s*)(qp + 32);
  }

  __hip_bfloat16* pw = Ps[wave];

  // ---- t-invariant staging pointers (advance by increment each tile) ----
  const __hip_bfloat16* kp[4];
  const __hip_bfloat16* vp[4];
  int cdst[4];
  {
    const __hip_bfloat16* kgbase = qkv + base_t * E3 + E_DIM + h * 64;
    const __hip_bfloat16* vgbase = Vt + (size_t)bh * 64 * 1024;
#pragma unroll
    for (int i = 0; i < 4; ++i) {
      int c = tid + i * 256;
      cdst[i] = c * 16;
      int row = c >> 3, lc = c & 7;
      int gc = lc ^ (row & 7);
      kp[i] = kgbase + (size_t)row * E3 + gc * 8;
      int d = c >> 4, lcv = c & 15;
      int gv = lcv ^ (d & 15);
      vp[i] = vgbase + (size_t)d * 1024 + gv * 8;
    }
  }

  // ---- t-invariant compute addresses ----
  const int cho0 = (quad ^ (l16 & 7)) << 4;          // QK ak0 chunk
  const int cho1 = ((quad + 4) ^ (l16 & 7)) << 4;    // QK ak1 chunk
  const char* krbase = (const char*)Ks + l16 * 128;  // + nt*2048 (imm offset)
  char* pwr[8];                                      // P write pointers
#pragma unroll
  for (int nt = 0; nt < 8; ++nt) {
    int lcq = 2 * nt + (quad >> 1);
    pwr[nt] = (char*)pw + l16 * 256 + ((lcq ^ l16) * 16) + (quad & 1) * 8;
  }
  const char* pvp[4];                                // PV: P read pointers
  int vvo[4];                                        // PV: Vs base offsets
#pragma unroll
  for (int ks = 0; ks < 4; ++ks) {
    int pch16 = (((ks * 4 + quad) ^ l16) << 4);
    pvp[ks] = (char*)pw + l16 * 256 + pch16;
    vvo[ks] = l16 * 256 + pch16;                     // + dt*4096
  }

  constexpr float CEXP = 0.18033688011112042f;  // 0.125 * log2(e)
  float m_prev = -3.0e38f;
  float mc = m_prev * CEXP;
  float lsum = 0.f;
  v4f oc[4];
#pragma unroll
  for (int dt = 0; dt < 4; ++dt) oc[dt] = (v4f){0.f, 0.f, 0.f, 0.f};

#pragma unroll 1
  for (int t = 0; t < 8; ++t) {
    __syncthreads();  // all waves done reading previous Ks/Vs tile
#pragma unroll
    for (int i = 0; i < 4; ++i) gload_lds16(kp[i], (char*)Ks + cdst[i]);
#pragma unroll
    for (int i = 0; i < 4; ++i) gload_lds16(vp[i], (char*)Vs + cdst[i]);
#pragma unroll
    for (int i = 0; i < 4; ++i) { kp[i] += (size_t)128 * E3; vp[i] += 128; }
    __syncthreads();  // staged (barrier drains vmcnt)

    // ---- scores^T: D[kc][q] ; 8 kc-tiles of 16 ----
    v4f accT[8];
    __builtin_amdgcn_s_setprio(1);
#pragma unroll
    for (int nt = 0; nt < 8; ++nt) {
      const char* kr = krbase + nt * 2048;
      v8s ak0 = *(const v8s*)(kr + cho0);
      v8s ak1 = *(const v8s*)(kr + cho1);
      v4f z = {0.f, 0.f, 0.f, 0.f};
      z = __builtin_amdgcn_mfma_f32_16x16x32_bf16(ak0, qb0, z, 0, 0, 0);
      accT[nt] = __builtin_amdgcn_mfma_f32_16x16x32_bf16(ak1, qb1, accT[nt] = z, 0, 0, 0);
    }
    __builtin_amdgcn_s_setprio(0);

    // ---- online softmax (per-lane q = l16; quads hold disjoint k-slices) ----
    float mt = -3.0e38f;
#pragma unroll
    for (int nt = 0; nt < 8; ++nt)
      mt = fmaxf(mt, fmaxf(fmaxf(accT[nt][0], accT[nt][1]),
                           fmaxf(accT[nt][2], accT[nt][3])));
    mt = fmaxf(mt, __shfl_xor(mt, 16, 64));
    mt = fmaxf(mt, __shfl_xor(mt, 32, 64));
    // T13 defer-max: only rescale when the running max grows materially.
    // P bounded by exp(0.125*48)=e^6~403 (bf16-safe); exact up to fp rounding.
    if (__any(mt > m_prev + 48.0f)) {
      float m_new = fmaxf(m_prev, mt);
      float mcn = m_new * CEXP;
      float alpha = exp2f(m_prev * CEXP - mcn);
      m_prev = m_new;
      mc = mcn;
      lsum *= alpha;
      if (quad == 0) stats[wave][l16] = alpha;
      v4f a4 = *(v4f*)&stats[wave][quad * 4];
#pragma unroll
      for (int dt = 0; dt < 4; ++dt)
#pragma unroll
        for (int r = 0; r < 4; ++r) oc[dt][r] *= a4[r];
    }
    float ts = 0.f;
#pragma unroll
    for (int nt = 0; nt < 8; ++nt)
#pragma unroll
      for (int r = 0; r < 4; ++r) {
        float e = exp2f(fmaf(accT[nt][r], CEXP, -mc));
        accT[nt][r] = e;
        ts += e;
      }
    lsum += ts;
    // write P rows (q=l16): 4 contiguous k per reg-group -> b64
#pragma unroll
    for (int nt = 0; nt < 8; ++nt) {
      __hip_bfloat16 pk[4] __attribute__((aligned(8)));
#pragma unroll
      for (int r = 0; r < 4; ++r) pk[r] = __float2bfloat16(accT[nt][r]);
      *(uint2*)pwr[nt] = *(uint2*)pk;
    }
    // ---- PV: A=P[q][k], B=Vs[d][k] ----
    __builtin_amdgcn_s_setprio(1);
#pragma unroll
    for (int ks = 0; ks < 4; ++ks) {
      v8s ap = *(const v8s*)pvp[ks];
#pragma unroll
      for (int dt = 0; dt < 4; ++dt) {
        v8s bv = *(const v8s*)((char*)Vs + vvo[ks] + dt * 4096);
        oc[dt] = __builtin_amdgcn_mfma_f32_16x16x32_bf16(ap, bv, oc[dt], 0, 0, 0);
      }
    }
    __builtin_amdgcn_s_setprio(0);
  }

  // ---- epilogue: finish l, normalize, store ----
  lsum += __shfl_xor(lsum, 16, 64);
  lsum += __shfl_xor(lsum, 32, 64);
  if (quad == 0) stats[wave][l16] = lsum;
  v4f l4 = *(v4f*)&stats[wave][quad * 4];
  float inv[4];
#pragma unroll
  for (int r = 0; r < 4; ++r) inv[r] = 1.0f / l4[r];
#pragma unroll
  for (int dt = 0; dt < 4; ++dt)
#pragma unroll
    for (int r = 0; r < 4; ++r) {
      int tok = q0 + wave * 16 + quad * 4 + r;
      attn[(base_t + tok) * (size_t)E_DIM + h * 64 + dt * 16 + l16] =
          __float2bfloat16(oc[dt][r] * inv[r]);
    }
}

// ---------- launch ----------
extern "C" void kernel_launch(void* const* d_in, const int* in_sizes, int n_in,
                              void* d_out, int out_size, void* d_ws, size_t ws_size,
                              hipStream_t stream) {
  const float* hidden = (const float*)d_in[0];
  const float* ln1_w = (const float*)d_in[1];
  const float* ln1_b = (const float*)d_in[2];
  const float* ln2_w = (const float*)d_in[3];
  const float* ln2_b = (const float*)d_in[4];
  const float* W_qkv = (const float*)d_in[5];
  const float* b_qkv = (const float*)d_in[6];
  const float* W_out = (const float*)d_in[7];
  const float* b_out = (const float*)d_in[8];
  const float* W_fc1 = (const float*)d_in[9];
  const float* b_fc1 = (const float*)d_in[10];
  const float* W_fc2 = (const float*)d_in[11];
  const float* b_fc2 = (const float*)d_in[12];

  // ---- workspace plan (~250.7 MB) ----
  char* ws = (char*)d_ws;
  size_t off = 0;
  auto alloc = [&](size_t bytes) {
    void* p = ws + off;
    off += (bytes + 255) & ~(size_t)255;
    return p;
  };
  int8_t* qw_qkv = (int8_t*)alloc((size_t)3 * E_DIM * E_DIM);
  int8_t* qw_out = (int8_t*)alloc((size_t)E_DIM * E_DIM);
  int8_t* qw_fc1 = (int8_t*)alloc((size_t)F_DIM * E_DIM);
  int8_t* qw_fc2 = (int8_t*)alloc((size_t)E_DIM * F_DIM);
  float* sw_qkv = (float*)alloc((size_t)3 * E_DIM * 4);
  float* sw_out = (float*)alloc((size_t)E_DIM * 4);
  float* sw_fc1 = (float*)alloc((size_t)F_DIM * 4);
  float* sw_fc2 = (float*)alloc((size_t)E_DIM * 4);
  float* sx1 = (float*)alloc((size_t)T_DIM * 4);
  float* sa  = (float*)alloc((size_t)T_DIM * 4);
  float* sx2 = (float*)alloc((size_t)T_DIM * 4);
  float* sg  = (float*)alloc((size_t)T_DIM * 4);
  int8_t* qx = (int8_t*)alloc((size_t)T_DIM * E_DIM);              // reused 3x
  char* R = (char*)alloc((size_t)T_DIM * 3 * E_DIM * 2 +           // 209,715,200 B
                         (size_t)T_DIM * E_DIM * 4);
  __hip_bfloat16* qkv_bf = (__hip_bfloat16*)R;
  __hip_bfloat16* attn_bf = (__hip_bfloat16*)(R + (size_t)T_DIM * 3 * E_DIM * 2);
  __hip_bfloat16* Vt = (__hip_bfloat16*)(R + (size_t)T_DIM * 3 * E_DIM * 2 +
                                         (size_t)T_DIM * E_DIM * 2);
  __hip_bfloat16* f1_bf = (__hip_bfloat16*)R;
  int8_t* qg = (int8_t*)R;                                         // strided lda=2F
  float* hidden2 = (float*)d_out;

  // 1) weight quantization
  wquant_kernel<<<3 * E_DIM, 256, 0, stream>>>(W_qkv, qw_qkv, sw_qkv, E_DIM);
  wquant_kernel<<<E_DIM, 256, 0, stream>>>(W_out, qw_out, sw_out, E_DIM);
  wquant_kernel<<<F_DIM, 256, 0, stream>>>(W_fc1, qw_fc1, sw_fc1, E_DIM);
  wquant_kernel<<<E_DIM, 256, 0, stream>>>(W_fc2, qw_fc2, sw_fc2, F_DIM);
  // 2) rms1 + quant
  rms_quant_kernel<<<T_DIM, 256, 0, stream>>>(hidden, ln1_w, ln1_b, qx, sx1);
  // 3) QKV gemm -> bf16   (grid = 64 * 15 = 960 blocks)
  gemm256_i8<0><<<(T_DIM / 256) * (3 * E_DIM / 256), 512, 0, stream>>>(
      qx, qw_qkv, sx1, sw_qkv, b_qkv, nullptr, qkv_bf, T_DIM, 3 * E_DIM, E_DIM, E_DIM);
  // 4) V transpose
  vt_kernel<<<dim3(S_LEN / 64, B_SZ * NH), 256, 0, stream>>>(qkv_bf, Vt);
  // 5) flash MFMA attention -> bf16  (1D grid 5120, XCD-locality swizzle)
  attn_flash_kernel<<<(S_LEN / 64) * B_SZ * NH, 256, 0, stream>>>(qkv_bf, Vt, attn_bf);
  // 6) quant attn
  row_quant_bf_kernel<<<T_DIM, 256, 0, stream>>>(attn_bf, qx, sa);
  // 7) out proj + residual -> hidden2 (= d_out)  (grid = 128 * 10 = 1280)
  gemm128_i8<1><<<(T_DIM / 128) * (E_DIM / 128), 256, 0, stream>>>(
      qx, qw_out, sa, sw_out, b_out, hidden, hidden2, T_DIM, E_DIM, E_DIM, E_DIM);
  // 8) rms2 + quant
  rms_quant_kernel<<<T_DIM, 256, 0, stream>>>(hidden2, ln2_w, ln2_b, qx, sx2);
  // 9) FC1 gemm -> bf16   (grid = 64 * 20 = 1280)
  gemm256_i8<0><<<(T_DIM / 256) * (F_DIM / 256), 512, 0, stream>>>(
      qx, qw_fc1, sx2, sw_fc1, b_fc1, nullptr, f1_bf, T_DIM, F_DIM, E_DIM, E_DIM);
  // 10) gelu + quant (in-place strided int8 rows inside f1 buffer)
  gelu_quant_kernel<<<T_DIM, 256, 0, stream>>>(f1_bf, qg, sg);
  // 11) FC2 gemm + residual -> d_out (in-place, element-private)
  gemm128_i8<1><<<(T_DIM / 128) * (E_DIM / 128), 256, 0, stream>>>(
      qg, qw_fc2, sg, sw_fc2, b_fc2, hidden2, (float*)d_out, T_DIM, E_DIM, F_DIM, 2 * F_DIM);
}

// Round 7
// 1051.705 us; speedup vs baseline: 1.0057x; 1.0057x over previous
//
#include <hip/hip_runtime.h>
#include <hip/hip_bf16.h>
#include <stdint.h>

#define E_DIM 1280
#define F_DIM 5120
#define T_DIM 16384
#define B_SZ  16
#define S_LEN 1024
#define NH    20

typedef int v4i __attribute__((ext_vector_type(4)));
typedef __attribute__((ext_vector_type(8))) short v8s;
typedef __attribute__((ext_vector_type(4))) float v4f;

// ---------- helpers ----------
__device__ __forceinline__ float wred_sum(float v) {
#pragma unroll
  for (int m = 32; m > 0; m >>= 1) v += __shfl_xor(v, m, 64);
  return v;
}
__device__ __forceinline__ float wred_max(float v) {
#pragma unroll
  for (int m = 32; m > 0; m >>= 1) v = fmaxf(v, __shfl_xor(v, m, 64));
  return v;
}
__device__ __forceinline__ void gload_lds16(const void* g, void* l) {
  __builtin_amdgcn_global_load_lds((const __attribute__((address_space(1))) void*)g,
                                   (__attribute__((address_space(3))) void*)l, 16, 0, 0);
}

// ---------- per-output-channel weight quant ----------
__global__ __launch_bounds__(256) void wquant_kernel(
    const float* __restrict__ W, int8_t* __restrict__ qw, float* __restrict__ sw, int K) {
  __shared__ float red[4];
  const int row = blockIdx.x;
  const int tid = threadIdx.x;
  const float* wr = W + (size_t)row * K;
  float amax = 0.f;
  for (int c = tid; c < K; c += 256) amax = fmaxf(amax, fabsf(wr[c]));
  amax = wred_max(amax);
  if ((tid & 63) == 0) red[tid >> 6] = amax;
  __syncthreads();
  amax = fmaxf(fmaxf(red[0], red[1]), fmaxf(red[2], red[3]));
  float sc = amax * (1.0f / 127.0f);
  if (tid == 0) sw[row] = sc;
  for (int c = tid; c < K; c += 256) {
    float qv = rintf(wr[c] / sc);
    qw[(size_t)row * K + c] = (int8_t)qv;
  }
}

// ---------- RMSNorm(+bias) + per-token quant (E=1280) ----------
__global__ __launch_bounds__(256) void rms_quant_kernel(
    const float* __restrict__ x, const float* __restrict__ w, const float* __restrict__ b,
    int8_t* __restrict__ q, float* __restrict__ s) {
  __shared__ float red[4];
  const int row = blockIdx.x;
  const int tid = threadIdx.x;
  const float* xr = x + (size_t)row * E_DIM;
  float vals[5];
  float ss = 0.f;
#pragma unroll
  for (int i = 0; i < 5; ++i) {
    float v = xr[tid + i * 256];
    vals[i] = v; ss += v * v;
  }
  ss = wred_sum(ss);
  if ((tid & 63) == 0) red[tid >> 6] = ss;
  __syncthreads();
  ss = red[0] + red[1] + red[2] + red[3];
  float rstd = rsqrtf(ss * (1.0f / E_DIM) + 1e-6f);
  float y[5]; float amax = 0.f;
#pragma unroll
  for (int i = 0; i < 5; ++i) {
    int c = tid + i * 256;
    float v = vals[i] * rstd * w[c] + b[c];
    y[i] = v;
    amax = fmaxf(amax, fabsf(v));
  }
  amax = wred_max(amax);
  __syncthreads();
  if ((tid & 63) == 0) red[tid >> 6] = amax;
  __syncthreads();
  amax = fmaxf(fmaxf(red[0], red[1]), fmaxf(red[2], red[3]));
  float sc = amax * (1.0f / 127.0f);
  if (tid == 0) s[row] = sc;
#pragma unroll
  for (int i = 0; i < 5; ++i) {
    int c = tid + i * 256;
    float qv = rintf(y[i] / sc);
    qv = fminf(fmaxf(qv, -127.f), 127.f);
    q[(size_t)row * E_DIM + c] = (int8_t)qv;
  }
}

// ---------- per-token quant (E=1280, bf16 in) ----------
__global__ __launch_bounds__(256) void row_quant_bf_kernel(
    const __hip_bfloat16* __restrict__ x, int8_t* __restrict__ q, float* __restrict__ s) {
  __shared__ float red[4];
  const int row = blockIdx.x;
  const int tid = threadIdx.x;
  const __hip_bfloat16* xr = x + (size_t)row * E_DIM;
  float vals[5]; float amax = 0.f;
#pragma unroll
  for (int i = 0; i < 5; ++i) {
    float v = __bfloat162float(xr[tid + i * 256]);
    vals[i] = v;
    amax = fmaxf(amax, fabsf(v));
  }
  amax = wred_max(amax);
  if ((tid & 63) == 0) red[tid >> 6] = amax;
  __syncthreads();
  amax = fmaxf(fmaxf(red[0], red[1]), fmaxf(red[2], red[3]));
  float sc = amax * (1.0f / 127.0f);
  if (tid == 0) s[row] = sc;
#pragma unroll
  for (int i = 0; i < 5; ++i) {
    int c = tid + i * 256;
    float qv = rintf(vals[i] / sc);
    qv = fminf(fmaxf(qv, -127.f), 127.f);
    q[(size_t)row * E_DIM + c] = (int8_t)qv;
  }
}

// ---------- exact GELU + per-token quant (F=5120, bf16 in, int8 in-place) ----------
__global__ __launch_bounds__(256) void gelu_quant_kernel(
    const __hip_bfloat16* __restrict__ f1, int8_t* __restrict__ q, float* __restrict__ s) {
  __shared__ float red[4];
  const int row = blockIdx.x;
  const int tid = threadIdx.x;
  const __hip_bfloat16* xr = f1 + (size_t)row * F_DIM;
  float g[20]; float amax = 0.f;
#pragma unroll
  for (int i = 0; i < 20; ++i) {
    float v = __bfloat162float(xr[tid + i * 256]);
    float gv = 0.5f * v * (1.0f + erff(v * 0.70710678118654752440f));
    g[i] = gv;
    amax = fmaxf(amax, fabsf(gv));
  }
  amax = wred_max(amax);
  if ((tid & 63) == 0) red[tid >> 6] = amax;
  __syncthreads();
  amax = fmaxf(fmaxf(red[0], red[1]), fmaxf(red[2], red[3]));
  float sc = amax * (1.0f / 127.0f);
  if (tid == 0) s[row] = sc;
  int8_t* qr = q + (size_t)row * (2 * F_DIM);   // strided in-place rows
#pragma unroll
  for (int i = 0; i < 20; ++i) {
    int c = tid + i * 256;
    float qv = rintf(g[i] / sc);
    qv = fminf(fmaxf(qv, -127.f), 127.f);
    qr[c] = (int8_t)qv;
  }
}

// ============================================================================
// int8 GEMM, 256x256 tile, 8 waves, ring-of-4 K-tiles (BK=64), 16x16x64 MFMA.
// (conflict-free frag-read pattern; measured 0 LDS bank conflicts)
// ============================================================================
template <int MODE>
__global__ __launch_bounds__(512, 2) void gemm256_i8(
    const int8_t* __restrict__ A, const int8_t* __restrict__ B,
    const float* __restrict__ sx, const float* __restrict__ sw,
    const float* __restrict__ bias, const float* __restrict__ resid,
    void* __restrict__ outp, int M, int N, int K, int lda) {
  __shared__ __align__(16) int8_t As[2][2][256 * 64];
  __shared__ __align__(16) int8_t Bs[2][2][256 * 64];

  const int tid = threadIdx.x;
  const int lane = tid & 63;
  const int wave = tid >> 6;
  const int wm = wave >> 2;                       // 0..1  (M half)
  const int wn = wave & 3;                        // 0..3  (N quarter)
  const int l16 = lane & 15;
  const int quad = lane >> 4;
  const int choff = (quad ^ ((l16 >> 1) & 3)) << 4;   // read-side swizzled chunk

  // XCD-aware bijective swizzle (all grids divisible by 8)
  const int nwg = gridDim.x;
  const int ntn = N >> 8;
  const int u = (blockIdx.x & 7) * (nwg >> 3) + (blockIdx.x >> 3);
  const int tm = u / ntn, tn = u % ntn;
  const int m0 = tm << 8, n0 = tn << 8;

  const int8_t* A_blk = A + (size_t)m0 * lda;
  const int8_t* B_blk = B + (size_t)n0 * K;

  const int r0 = tid >> 2;                              // staged row (0..127)
  const int sch = ((tid & 3) ^ ((tid >> 3) & 3)) << 4;  // stage-side inv swizzle

#define STAGE_A(KT, DST)                                                         \
  {                                                                              \
    gload_lds16(A_blk + (size_t)r0 * lda + (size_t)(KT)*64 + sch,                \
                (DST) + tid * 16);                                               \
    gload_lds16(A_blk + (size_t)(r0 + 128) * lda + (size_t)(KT)*64 + sch,        \
                (DST) + 8192 + tid * 16);                                        \
  }
#define STAGE_B(KT, DST)                                                         \
  {                                                                              \
    gload_lds16(B_blk + (size_t)r0 * K + (size_t)(KT)*64 + sch,                  \
                (DST) + tid * 16);                                               \
    gload_lds16(B_blk + (size_t)(r0 + 128) * K + (size_t)(KT)*64 + sch,          \
                (DST) + 8192 + tid * 16);                                        \
  }

  v4i acc[8][4];
#pragma unroll
  for (int i = 0; i < 8; ++i)
#pragma unroll
    for (int j = 0; j < 4; ++j) acc[i][j] = (v4i){0, 0, 0, 0};

  const int nk = K >> 6;          // K-tiles of 64
  const int niter = nk >> 1;      // pairs of K-tiles

  // ---- prologue: stage tiles 0,1 into pair 0; wait tile 0 (oldest 4 of 8) ----
  STAGE_A(0, &As[0][0][0]); STAGE_B(0, &Bs[0][0][0]);
  STAGE_A(1, &As[0][1][0]); STAGE_B(1, &Bs[0][1][0]);
  asm volatile("s_waitcnt vmcnt(4)" ::: "memory");
  asm volatile("s_barrier" ::: "memory");

#pragma unroll 1
  for (int i = 0; i < niter - 1; ++i) {
    const int pr = i & 1;
    const int kt2 = 2 * i + 2;
#pragma unroll
    for (int ph = 0; ph < 4; ++ph) {
      const int tt = ph >> 1;     // tile within pair
      const int qm = ph & 1;      // M half of fragments
      const int8_t* At = &As[pr][tt][0];
      const int8_t* Bt = &Bs[pr][tt][0];
      v4i af[4], bf[4];
#pragma unroll
      for (int ii = 0; ii < 4; ++ii)
        af[ii] = *(const v4i*)(At + (wm * 128 + qm * 64 + ii * 16 + l16) * 64 + choff);
#pragma unroll
      for (int jj = 0; jj < 4; ++jj)
        bf[jj] = *(const v4i*)(Bt + (wn * 64 + jj * 16 + l16) * 64 + choff);
      // stage one half-matrix of the next pair's tile (2 loads)
      if (qm == 0) {
        STAGE_A(kt2 + tt, &As[pr ^ 1][tt][0]);
      } else {
        STAGE_B(kt2 + tt, &Bs[pr ^ 1][tt][0]);
      }
      asm volatile("s_barrier" ::: "memory");
      __builtin_amdgcn_s_setprio(1);
#pragma unroll
      for (int ii = 0; ii < 4; ++ii)
#pragma unroll
        for (int jj = 0; jj < 4; ++jj)
          acc[qm * 4 + ii][jj] = __builtin_amdgcn_mfma_i32_16x16x64_i8(
              af[ii], bf[jj], acc[qm * 4 + ii][jj], 0, 0, 0);
      __builtin_amdgcn_s_setprio(0);
      if (qm == 1) asm volatile("s_waitcnt vmcnt(4)" ::: "memory");
      asm volatile("s_barrier" ::: "memory");
    }
  }

  // ---- peeled final pair: no staging; drain remaining tile at phase 1 ----
  {
    const int pr = (niter - 1) & 1;
#pragma unroll
    for (int ph = 0; ph < 4; ++ph) {
      const int tt = ph >> 1;
      const int qm = ph & 1;
      const int8_t* At = &As[pr][tt][0];
      const int8_t* Bt = &Bs[pr][tt][0];
      v4i af[4], bf[4];
#pragma unroll
      for (int ii = 0; ii < 4; ++ii)
        af[ii] = *(const v4i*)(At + (wm * 128 + qm * 64 + ii * 16 + l16) * 64 + choff);
#pragma unroll
      for (int jj = 0; jj < 4; ++jj)
        bf[jj] = *(const v4i*)(Bt + (wn * 64 + jj * 16 + l16) * 64 + choff);
      asm volatile("s_barrier" ::: "memory");
      __builtin_amdgcn_s_setprio(1);
#pragma unroll
      for (int ii = 0; ii < 4; ++ii)
#pragma unroll
        for (int jj = 0; jj < 4; ++jj)
          acc[qm * 4 + ii][jj] = __builtin_amdgcn_mfma_i32_16x16x64_i8(
              af[ii], bf[jj], acc[qm * 4 + ii][jj], 0, 0, 0);
      __builtin_amdgcn_s_setprio(0);
      if (ph == 1) asm volatile("s_waitcnt vmcnt(0)" ::: "memory");
      asm volatile("s_barrier" ::: "memory");
    }
  }
#undef STAGE_A
#undef STAGE_B

  // ---- epilogue ----
  float swv[4], bv[4];
#pragma unroll
  for (int jj = 0; jj < 4; ++jj) {
    int n = n0 + wn * 64 + jj * 16 + l16;
    swv[jj] = sw[n];
    bv[jj] = bias[n];
  }
#pragma unroll
  for (int mf = 0; mf < 8; ++mf) {
#pragma unroll
    for (int r = 0; r < 4; ++r) {
      int m = m0 + wm * 128 + mf * 16 + quad * 4 + r;
      float sxm = sx[m];
#pragma unroll
      for (int jj = 0; jj < 4; ++jj) {
        int n = n0 + wn * 64 + jj * 16 + l16;
        float v = (float)acc[mf][jj][r] * (sxm * swv[jj]) + bv[jj];
        if constexpr (MODE == 0) {
          ((__hip_bfloat16*)outp)[(size_t)m * N + n] = __float2bfloat16(v);
        } else {
          ((float*)outp)[(size_t)m * N + n] = v + resid[(size_t)m * N + n];
        }
      }
    }
  }
}

// ============================================================================
// int8 GEMM, 128x128 tile, 4 waves, ring-of-4 K-tiles, 16x16x64 MFMA.
// 64 KiB LDS -> 2 blocks/CU; grid 1280 = 5 exact dispatch rounds.
// ============================================================================
template <int MODE>
__global__ __launch_bounds__(256, 2) void gemm128_i8(
    const int8_t* __restrict__ A, const int8_t* __restrict__ B,
    const float* __restrict__ sx, const float* __restrict__ sw,
    const float* __restrict__ bias, const float* __restrict__ resid,
    void* __restrict__ outp, int M, int N, int K, int lda) {
  __shared__ __align__(16) int8_t As[4][128 * 64];
  __shared__ __align__(16) int8_t Bs[4][128 * 64];

  const int tid = threadIdx.x;
  const int lane = tid & 63;
  const int wave = tid >> 6;
  const int wm = wave >> 1;                       // 0..1
  const int wn = wave & 1;                        // 0..1
  const int l16 = lane & 15;
  const int quad = lane >> 4;
  const int choff = (quad ^ ((l16 >> 1) & 3)) << 4;   // conflict-free pattern

  // XCD-aware bijective swizzle (grid divisible by 8)
  const int nwg = gridDim.x;
  const int ntn = N >> 7;
  const int u = (blockIdx.x & 7) * (nwg >> 3) + (blockIdx.x >> 3);
  const int tm = u / ntn, tn = u % ntn;
  const int m0 = tm << 7, n0 = tn << 7;

  const int8_t* A_blk = A + (size_t)m0 * lda;
  const int8_t* B_blk = B + (size_t)n0 * K;

  const int r0 = tid >> 2;                              // 0..63
  const int sch = ((tid & 3) ^ ((tid >> 3) & 3)) << 4;

#define STAGE_A(KT, SLOT)                                                        \
  {                                                                              \
    gload_lds16(A_blk + (size_t)r0 * lda + (size_t)(KT)*64 + sch,                \
                &As[SLOT][tid * 16]);                                            \
    gload_lds16(A_blk + (size_t)(r0 + 64) * lda + (size_t)(KT)*64 + sch,         \
                &As[SLOT][4096 + tid * 16]);                                     \
  }
#define STAGE_B(KT, SLOT)                                                        \
  {                                                                              \
    gload_lds16(B_blk + (size_t)r0 * K + (size_t)(KT)*64 + sch,                  \
                &Bs[SLOT][tid * 16]);                                            \
    gload_lds16(B_blk + (size_t)(r0 + 64) * K + (size_t)(KT)*64 + sch,           \
                &Bs[SLOT][4096 + tid * 16]);                                     \
  }

#define KTILE(SLOT, STAGE_STMT, WAIT_STMT)                                       \
  {                                                                              \
    const int8_t* At = &As[SLOT][0];                                             \
    const int8_t* Bt = &Bs[SLOT][0];                                             \
    v4i af[4], bf[4];                                                            \
    _Pragma("unroll") for (int ii = 0; ii < 4; ++ii)                             \
        af[ii] = *(const v4i*)(At + (wm * 64 + ii * 16 + l16) * 64 + choff);     \
    _Pragma("unroll") for (int jj = 0; jj < 4; ++jj)                             \
        bf[jj] = *(const v4i*)(Bt + (wn * 64 + jj * 16 + l16) * 64 + choff);     \
    STAGE_STMT;                                                                  \
    asm volatile("s_barrier" ::: "memory");                                      \
    __builtin_amdgcn_s_setprio(1);                                               \
    _Pragma("unroll") for (int ii = 0; ii < 4; ++ii)                             \
        _Pragma("unroll") for (int jj = 0; jj < 4; ++jj)                         \
            acc[ii][jj] = __builtin_amdgcn_mfma_i32_16x16x64_i8(                 \
                af[ii], bf[jj], acc[ii][jj], 0, 0, 0);                           \
    __builtin_amdgcn_s_setprio(0);                                               \
    WAIT_STMT;                                                                   \
    asm volatile("s_barrier" ::: "memory");                                      \
  }

  v4i acc[4][4];
#pragma unroll
  for (int i = 0; i < 4; ++i)
#pragma unroll
    for (int j = 0; j < 4; ++j) acc[i][j] = (v4i){0, 0, 0, 0};

  const int nk = K >> 6;          // >= 4 for all call sites

  // ---- prologue: stage tiles 0,1,2 (12 loads); wait tile 0 (oldest 4) ----
  STAGE_A(0, 0); STAGE_B(0, 0);
  STAGE_A(1, 1); STAGE_B(1, 1);
  STAGE_A(2, 2); STAGE_B(2, 2);
  asm volatile("s_waitcnt vmcnt(8)" ::: "memory");
  asm volatile("s_barrier" ::: "memory");

#pragma unroll 1
  for (int kt = 0; kt < nk - 3; ++kt) {
    const int sl = kt & 3;
    const int s3 = (kt + 3) & 3;
    KTILE(sl, { STAGE_A(kt + 3, s3); STAGE_B(kt + 3, s3); },
          asm volatile("s_waitcnt vmcnt(8)" ::: "memory"));
  }
  // ---- peel last 3 K-tiles (no staging; drain 8 -> 4 -> 0) ----
  KTILE((nk - 3) & 3, ((void)0), asm volatile("s_waitcnt vmcnt(4)" ::: "memory"));
  KTILE((nk - 2) & 3, ((void)0), asm volatile("s_waitcnt vmcnt(0)" ::: "memory"));
  KTILE((nk - 1) & 3, ((void)0), ((void)0));
#undef KTILE
#undef STAGE_A
#undef STAGE_B

  // ---- epilogue (16x16 C layout: col=lane&15, row=quad*4+r) ----
  float swv[4], bv[4];
#pragma unroll
  for (int jj = 0; jj < 4; ++jj) {
    int n = n0 + wn * 64 + jj * 16 + l16;
    swv[jj] = sw[n];
    bv[jj] = bias[n];
  }
#pragma unroll
  for (int ii = 0; ii < 4; ++ii) {
#pragma unroll
    for (int r = 0; r < 4; ++r) {
      int m = m0 + wm * 64 + ii * 16 + quad * 4 + r;
      float sxm = sx[m];
#pragma unroll
      for (int jj = 0; jj < 4; ++jj) {
        int n = n0 + wn * 64 + jj * 16 + l16;
        float v = (float)acc[ii][jj][r] * (sxm * swv[jj]) + bv[jj];
        if constexpr (MODE == 0) {
          ((__hip_bfloat16*)outp)[(size_t)m * N + n] = __float2bfloat16(v);
        } else {
          ((float*)outp)[(size_t)m * N + n] = v + resid[(size_t)m * N + n];
        }
      }
    }
  }
}

// ---------- V transpose: Vt[bh][d][k] = V[b,k,h,d] ----------
__global__ __launch_bounds__(256) void vt_kernel(
    const __hip_bfloat16* __restrict__ qkv, __hip_bfloat16* __restrict__ Vt) {
  __shared__ __hip_bfloat16 tile[64][72];
  const int bh = blockIdx.y, kc = blockIdx.x;
  const int b = bh / NH, h = bh % NH;
  const int tid = threadIdx.x;
  const size_t base = ((size_t)b * S_LEN + (size_t)kc * 64) * (3 * E_DIM) + 2 * E_DIM + h * 64;
#pragma unroll
  for (int i = 0; i < 2; ++i) {
    int idx = tid + i * 256;
    int row = idx >> 3, c8 = (idx & 7) * 8;
    *(uint4*)&tile[row][c8] = *(const uint4*)(qkv + base + (size_t)row * (3 * E_DIM) + c8);
  }
  __syncthreads();
#pragma unroll
  for (int i = 0; i < 2; ++i) {
    int idx = tid + i * 256;
    int d = idx >> 3, k8 = (idx & 7) * 8;
    __hip_bfloat16 v[8] __attribute__((aligned(16)));
#pragma unroll
    for (int j = 0; j < 8; ++j) v[j] = tile[k8 + j][d];
    *(uint4*)&Vt[((size_t)bh * 64 + d) * 1024 + (size_t)kc * 64 + k8] = *(uint4*)v;
  }
}

// ---------- flash MFMA attention: r3-exact (175us measured) + quarter-P ----------
// ONLY change vs the measured-best r3 kernel: Ps shrunk 16KB -> 5KB (PV runs
// in 4 k-32 blocks, P staged per-block; same-wave DS in-order makes the
// write->read exact without barriers) so LDS = 38.1KB -> 4 blocks/CU
// (16 waves/CU, up from 3 blocks/12 waves). Grid/softmax/staging unchanged.
__global__ __launch_bounds__(256, 4) void attn_flash_kernel(
    const __hip_bfloat16* __restrict__ qkv, const __hip_bfloat16* __restrict__ Vt,
    __hip_bfloat16* __restrict__ attn) {
  constexpr int E3 = 3 * E_DIM;
  __shared__ __align__(16) __hip_bfloat16 Ks[128 * 64];   // [row][8 chunks, ^(row&7)]
  __shared__ __align__(16) __hip_bfloat16 Vs[64 * 128];   // [d][16 chunks, ^(d&15)]
  __shared__ __align__(16) __hip_bfloat16 Ps[4][16 * 40]; // quarter-P, 80B rows
  __shared__ float stats[4][16];

  const int tid = threadIdx.x;
  const int lane = tid & 63;
  const int wave = tid >> 6;
  const int l16 = lane & 15;
  const int quad = lane >> 4;
  const int bh = blockIdx.y;
  const int b = bh / NH, h = bh % NH;
  const int q0 = blockIdx.x * 64;
  const size_t base_t = (size_t)b * S_LEN;

  // Q B-fragments for this wave's 16 q-rows
  v8s qb0, qb1;
  {
    const __hip_bfloat16* qp =
        qkv + (base_t + q0 + wave * 16 + l16) * (size_t)E3 + h * 64 + quad * 8;
    qb0 = *(const v8s*)qp;
    qb1 = *(const v8s*)(qp + 32);
  }

  float m_prev = -3.0e38f;
  float lsum = 0.f;
  v4f oc[4];
#pragma unroll
  for (int dt = 0; dt < 4; ++dt) oc[dt] = (v4f){0.f, 0.f, 0.f, 0.f};

  const __hip_bfloat16* kgbase = qkv + base_t * E3 + E_DIM + h * 64;
  const __hip_bfloat16* vgbase = Vt + (size_t)bh * 64 * 1024;
  char* pw = (char*)Ps[wave];

#pragma unroll 1
  for (int t = 0; t < 8; ++t) {
    __syncthreads();  // all waves done reading previous Ks/Vs tile
#pragma unroll
    for (int i = 0; i < 4; ++i) {   // stage K tile: 128 rows x 128B
      int c = tid + i * 256;
      int row = c >> 3, lc = c & 7;
      int gc = lc ^ (row & 7);
      gload_lds16(kgbase + (size_t)(t * 128 + row) * E3 + gc * 8, (char*)Ks + c * 16);
    }
#pragma unroll
    for (int i = 0; i < 4; ++i) {   // stage V tile: 64 d x 256B
      int c = tid + i * 256;
      int d = c >> 4, lc = c & 15;
      int gc = lc ^ (d & 15);
      gload_lds16(vgbase + (size_t)d * 1024 + t * 128 + gc * 8, (char*)Vs + c * 16);
    }
    __syncthreads();  // staged (vmcnt drained by barrier semantics)

    // ---- scores^T: D[kc][q] ; 8 kc-tiles of 16 ----
    v4f accT[8];
#pragma unroll
    for (int nt = 0; nt < 8; ++nt) {
      int row = nt * 16 + l16;
      const char* kr = (const char*)Ks + row * 128;
      v8s ak0 = *(const v8s*)(kr + ((quad ^ (row & 7)) * 16));
      v8s ak1 = *(const v8s*)(kr + (((quad + 4) ^ (row & 7)) * 16));
      v4f z = {0.f, 0.f, 0.f, 0.f};
      z = __builtin_amdgcn_mfma_f32_16x16x32_bf16(ak0, qb0, z, 0, 0, 0);
      accT[nt] = __builtin_amdgcn_mfma_f32_16x16x32_bf16(ak1, qb1, accT[nt] = z, 0, 0, 0);
    }

    // ---- online softmax (per-lane q = l16; quads hold disjoint k-slices) ----
    float mt = -3.0e38f;
#pragma unroll
    for (int nt = 0; nt < 8; ++nt)
#pragma unroll
      for (int r = 0; r < 4; ++r) mt = fmaxf(mt, accT[nt][r]);
    mt = fmaxf(mt, __shfl_xor(mt, 16, 64));
    mt = fmaxf(mt, __shfl_xor(mt, 32, 64));
    float m_new = fmaxf(m_prev, mt);
    float alpha = __expf(0.125f * (m_prev - m_new));
    m_prev = m_new;
    float ts = 0.f;
#pragma unroll
    for (int nt = 0; nt < 8; ++nt)
#pragma unroll
      for (int r = 0; r < 4; ++r) {
        float e = __expf(0.125f * (accT[nt][r] - m_new));
        accT[nt][r] = e;
        ts += e;
      }
    lsum = lsum * alpha + ts;
    if (quad == 0) stats[wave][l16] = alpha;
    // rescale O (alpha for q=quad*4+r via LDS; same-wave DS ops are in-order)
    v4f a4 = *(v4f*)&stats[wave][quad * 4];
#pragma unroll
    for (int dt = 0; dt < 4; ++dt)
#pragma unroll
      for (int r = 0; r < 4; ++r) oc[dt][r] *= a4[r];

    // ---- PV in 4 k-32 blocks; quarter-P staged per block ----
    // write: lane(q=l16,quad) holds S[k=nt*16+quad*4+r][q]; within block j,
    // nt=2j+e2 -> k_local = e2*16+quad*4+r -> chunk 2*e2+(quad>>1), off (quad&1)*8.
    // read: A-frag P[q][quad*8..+7] = chunk quad. Both sides ^(q&3) swizzled.
#pragma unroll
    for (int j = 0; j < 4; ++j) {
#pragma unroll
      for (int e2 = 0; e2 < 2; ++e2) {
        int nt = 2 * j + e2;
        __hip_bfloat16 pk[4] __attribute__((aligned(8)));
#pragma unroll
        for (int r = 0; r < 4; ++r) pk[r] = __float2bfloat16(accT[nt][r]);
        int lcq = 2 * e2 + (quad >> 1);
        *(uint2*)(pw + l16 * 80 + ((lcq ^ (l16 & 3)) * 16) + (quad & 1) * 8) = *(uint2*)pk;
      }
      v8s ap = *(const v8s*)(pw + l16 * 80 + ((quad ^ (l16 & 3)) * 16));
#pragma unroll
      for (int dt = 0; dt < 4; ++dt) {
        int d = dt * 16 + l16;
        v8s bv = *(const v8s*)((char*)Vs + d * 256 + (((j * 4 + quad) ^ l16) * 16));
        oc[dt] = __builtin_amdgcn_mfma_f32_16x16x32_bf16(ap, bv, oc[dt], 0, 0, 0);
      }
    }
  }

  // ---- epilogue: finish l, normalize, store ----
  lsum += __shfl_xor(lsum, 16, 64);
  lsum += __shfl_xor(lsum, 32, 64);
  if (quad == 0) stats[wave][l16] = lsum;
  v4f l4 = *(v4f*)&stats[wave][quad * 4];
  float inv[4];
#pragma unroll
  for (int r = 0; r < 4; ++r) inv[r] = 1.0f / l4[r];
#pragma unroll
  for (int dt = 0; dt < 4; ++dt)
#pragma unroll
    for (int r = 0; r < 4; ++r) {
      int tok = q0 + wave * 16 + quad * 4 + r;
      attn[(base_t + tok) * (size_t)E_DIM + h * 64 + dt * 16 + l16] =
          __float2bfloat16(oc[dt][r] * inv[r]);
    }
}

// ---------- launch ----------
extern "C" void kernel_launch(void* const* d_in, const int* in_sizes, int n_in,
                              void* d_out, int out_size, void* d_ws, size_t ws_size,
                              hipStream_t stream) {
  const float* hidden = (const float*)d_in[0];
  const float* ln1_w = (const float*)d_in[1];
  const float* ln1_b = (const float*)d_in[2];
  const float* ln2_w = (const float*)d_in[3];
  const float* ln2_b = (const float*)d_in[4];
  const float* W_qkv = (const float*)d_in[5];
  const float* b_qkv = (const float*)d_in[6];
  const float* W_out = (const float*)d_in[7];
  const float* b_out = (const float*)d_in[8];
  const float* W_fc1 = (const float*)d_in[9];
  const float* b_fc1 = (const float*)d_in[10];
  const float* W_fc2 = (const float*)d_in[11];
  const float* b_fc2 = (const float*)d_in[12];

  // ---- workspace plan (~250.7 MB) ----
  char* ws = (char*)d_ws;
  size_t off = 0;
  auto alloc = [&](size_t bytes) {
    void* p = ws + off;
    off += (bytes + 255) & ~(size_t)255;
    return p;
  };
  int8_t* qw_qkv = (int8_t*)alloc((size_t)3 * E_DIM * E_DIM);
  int8_t* qw_out = (int8_t*)alloc((size_t)E_DIM * E_DIM);
  int8_t* qw_fc1 = (int8_t*)alloc((size_t)F_DIM * E_DIM);
  int8_t* qw_fc2 = (int8_t*)alloc((size_t)E_DIM * F_DIM);
  float* sw_qkv = (float*)alloc((size_t)3 * E_DIM * 4);
  float* sw_out = (float*)alloc((size_t)E_DIM * 4);
  float* sw_fc1 = (float*)alloc((size_t)F_DIM * 4);
  float* sw_fc2 = (float*)alloc((size_t)E_DIM * 4);
  float* sx1 = (float*)alloc((size_t)T_DIM * 4);
  float* sa  = (float*)alloc((size_t)T_DIM * 4);
  float* sx2 = (float*)alloc((size_t)T_DIM * 4);
  float* sg  = (float*)alloc((size_t)T_DIM * 4);
  int8_t* qx = (int8_t*)alloc((size_t)T_DIM * E_DIM);              // reused 3x
  char* R = (char*)alloc((size_t)T_DIM * 3 * E_DIM * 2 +           // 209,715,200 B
                         (size_t)T_DIM * E_DIM * 4);
  __hip_bfloat16* qkv_bf = (__hip_bfloat16*)R;
  __hip_bfloat16* attn_bf = (__hip_bfloat16*)(R + (size_t)T_DIM * 3 * E_DIM * 2);
  __hip_bfloat16* Vt = (__hip_bfloat16*)(R + (size_t)T_DIM * 3 * E_DIM * 2 +
                                         (size_t)T_DIM * E_DIM * 2);
  __hip_bfloat16* f1_bf = (__hip_bfloat16*)R;
  int8_t* qg = (int8_t*)R;                                         // strided lda=2F
  float* hidden2 = (float*)d_out;

  // 1) weight quantization
  wquant_kernel<<<3 * E_DIM, 256, 0, stream>>>(W_qkv, qw_qkv, sw_qkv, E_DIM);
  wquant_kernel<<<E_DIM, 256, 0, stream>>>(W_out, qw_out, sw_out, E_DIM);
  wquant_kernel<<<F_DIM, 256, 0, stream>>>(W_fc1, qw_fc1, sw_fc1, E_DIM);
  wquant_kernel<<<E_DIM, 256, 0, stream>>>(W_fc2, qw_fc2, sw_fc2, F_DIM);
  // 2) rms1 + quant
  rms_quant_kernel<<<T_DIM, 256, 0, stream>>>(hidden, ln1_w, ln1_b, qx, sx1);
  // 3) QKV gemm -> bf16   (grid = 64 * 15 = 960 blocks)
  gemm256_i8<0><<<(T_DIM / 256) * (3 * E_DIM / 256), 512, 0, stream>>>(
      qx, qw_qkv, sx1, sw_qkv, b_qkv, nullptr, qkv_bf, T_DIM, 3 * E_DIM, E_DIM, E_DIM);
  // 4) V transpose
  vt_kernel<<<dim3(S_LEN / 64, B_SZ * NH), 256, 0, stream>>>(qkv_bf, Vt);
  // 5) flash MFMA attention -> bf16  (r3 grid; 4 blocks/CU)
  attn_flash_kernel<<<dim3(S_LEN / 64, B_SZ * NH), 256, 0, stream>>>(qkv_bf, Vt, attn_bf);
  // 6) quant attn
  row_quant_bf_kernel<<<T_DIM, 256, 0, stream>>>(attn_bf, qx, sa);
  // 7) out proj + residual -> hidden2 (= d_out)  (grid = 128 * 10 = 1280)
  gemm128_i8<1><<<(T_DIM / 128) * (E_DIM / 128), 256, 0, stream>>>(
      qx, qw_out, sa, sw_out, b_out, hidden, hidden2, T_DIM, E_DIM, E_DIM, E_DIM);
  // 8) rms2 + quant
  rms_quant_kernel<<<T_DIM, 256, 0, stream>>>(hidden2, ln2_w, ln2_b, qx, sx2);
  // 9) FC1 gemm -> bf16   (grid = 64 * 20 = 1280)
  gemm256_i8<0><<<(T_DIM / 256) * (F_DIM / 256), 512, 0, stream>>>(
      qx, qw_fc1, sx2, sw_fc1, b_fc1, nullptr, f1_bf, T_DIM, F_DIM, E_DIM, E_DIM);
  // 10) gelu + quant (in-place strided int8 rows inside f1 buffer)
  gelu_quant_kernel<<<T_DIM, 256, 0, stream>>>(f1_bf, qg, sg);
  // 11) FC2 gemm + residual -> d_out (in-place, element-private)
  gemm128_i8<1><<<(T_DIM / 128) * (E_DIM / 128), 256, 0, stream>>>(
      qg, qw_fc2, sg, sw_fc2, b_fc2, hidden2, (float*)d_out, T_DIM, E_DIM, F_DIM, 2 * F_DIM);
}

// Round 8
// 1031.577 us; speedup vs baseline: 1.0253x; 1.0195x over previous
//
#include <hip/hip_runtime.h>
#include <hip/hip_bf16.h>
#include <stdint.h>

#define E_DIM 1280
#define F_DIM 5120
#define T_DIM 16384
#define B_SZ  16
#define S_LEN 1024
#define NH    20

typedef int v4i __attribute__((ext_vector_type(4)));
typedef __attribute__((ext_vector_type(8))) short v8s;
typedef __attribute__((ext_vector_type(4))) float v4f;

// ---------- helpers ----------
__device__ __forceinline__ float wred_sum(float v) {
#pragma unroll
  for (int m = 32; m > 0; m >>= 1) v += __shfl_xor(v, m, 64);
  return v;
}
__device__ __forceinline__ float wred_max(float v) {
#pragma unroll
  for (int m = 32; m > 0; m >>= 1) v = fmaxf(v, __shfl_xor(v, m, 64));
  return v;
}
__device__ __forceinline__ void gload_lds16(const void* g, void* l) {
  __builtin_amdgcn_global_load_lds((const __attribute__((address_space(1))) void*)g,
                                   (__attribute__((address_space(3))) void*)l, 16, 0, 0);
}

// ---------- per-output-channel weight quant ----------
__global__ __launch_bounds__(256) void wquant_kernel(
    const float* __restrict__ W, int8_t* __restrict__ qw, float* __restrict__ sw, int K) {
  __shared__ float red[4];
  const int row = blockIdx.x;
  const int tid = threadIdx.x;
  const float* wr = W + (size_t)row * K;
  float amax = 0.f;
  for (int c = tid; c < K; c += 256) amax = fmaxf(amax, fabsf(wr[c]));
  amax = wred_max(amax);
  if ((tid & 63) == 0) red[tid >> 6] = amax;
  __syncthreads();
  amax = fmaxf(fmaxf(red[0], red[1]), fmaxf(red[2], red[3]));
  float sc = amax * (1.0f / 127.0f);
  if (tid == 0) sw[row] = sc;
  for (int c = tid; c < K; c += 256) {
    float qv = rintf(wr[c] / sc);
    qw[(size_t)row * K + c] = (int8_t)qv;
  }
}

// ---------- RMSNorm(+bias) + per-token quant (E=1280) ----------
__global__ __launch_bounds__(256) void rms_quant_kernel(
    const float* __restrict__ x, const float* __restrict__ w, const float* __restrict__ b,
    int8_t* __restrict__ q, float* __restrict__ s) {
  __shared__ float red[4];
  const int row = blockIdx.x;
  const int tid = threadIdx.x;
  const float* xr = x + (size_t)row * E_DIM;
  float vals[5];
  float ss = 0.f;
#pragma unroll
  for (int i = 0; i < 5; ++i) {
    float v = xr[tid + i * 256];
    vals[i] = v; ss += v * v;
  }
  ss = wred_sum(ss);
  if ((tid & 63) == 0) red[tid >> 6] = ss;
  __syncthreads();
  ss = red[0] + red[1] + red[2] + red[3];
  float rstd = rsqrtf(ss * (1.0f / E_DIM) + 1e-6f);
  float y[5]; float amax = 0.f;
#pragma unroll
  for (int i = 0; i < 5; ++i) {
    int c = tid + i * 256;
    float v = vals[i] * rstd * w[c] + b[c];
    y[i] = v;
    amax = fmaxf(amax, fabsf(v));
  }
  amax = wred_max(amax);
  __syncthreads();
  if ((tid & 63) == 0) red[tid >> 6] = amax;
  __syncthreads();
  amax = fmaxf(fmaxf(red[0], red[1]), fmaxf(red[2], red[3]));
  float sc = amax * (1.0f / 127.0f);
  if (tid == 0) s[row] = sc;
#pragma unroll
  for (int i = 0; i < 5; ++i) {
    int c = tid + i * 256;
    float qv = rintf(y[i] / sc);
    qv = fminf(fmaxf(qv, -127.f), 127.f);
    q[(size_t)row * E_DIM + c] = (int8_t)qv;
  }
}

// ---------- per-token quant (E=1280, bf16 in) ----------
__global__ __launch_bounds__(256) void row_quant_bf_kernel(
    const __hip_bfloat16* __restrict__ x, int8_t* __restrict__ q, float* __restrict__ s) {
  __shared__ float red[4];
  const int row = blockIdx.x;
  const int tid = threadIdx.x;
  const __hip_bfloat16* xr = x + (size_t)row * E_DIM;
  float vals[5]; float amax = 0.f;
#pragma unroll
  for (int i = 0; i < 5; ++i) {
    float v = __bfloat162float(xr[tid + i * 256]);
    vals[i] = v;
    amax = fmaxf(amax, fabsf(v));
  }
  amax = wred_max(amax);
  if ((tid & 63) == 0) red[tid >> 6] = amax;
  __syncthreads();
  amax = fmaxf(fmaxf(red[0], red[1]), fmaxf(red[2], red[3]));
  float sc = amax * (1.0f / 127.0f);
  if (tid == 0) s[row] = sc;
#pragma unroll
  for (int i = 0; i < 5; ++i) {
    int c = tid + i * 256;
    float qv = rintf(vals[i] / sc);
    qv = fminf(fmaxf(qv, -127.f), 127.f);
    q[(size_t)row * E_DIM + c] = (int8_t)qv;
  }
}

// ---------- exact GELU + per-token quant (F=5120, bf16 in, int8 in-place) ----------
__global__ __launch_bounds__(256) void gelu_quant_kernel(
    const __hip_bfloat16* __restrict__ f1, int8_t* __restrict__ q, float* __restrict__ s) {
  __shared__ float red[4];
  const int row = blockIdx.x;
  const int tid = threadIdx.x;
  const __hip_bfloat16* xr = f1 + (size_t)row * F_DIM;
  float g[20]; float amax = 0.f;
#pragma unroll
  for (int i = 0; i < 20; ++i) {
    float v = __bfloat162float(xr[tid + i * 256]);
    float gv = 0.5f * v * (1.0f + erff(v * 0.70710678118654752440f));
    g[i] = gv;
    amax = fmaxf(amax, fabsf(gv));
  }
  amax = wred_max(amax);
  if ((tid & 63) == 0) red[tid >> 6] = amax;
  __syncthreads();
  amax = fmaxf(fmaxf(red[0], red[1]), fmaxf(red[2], red[3]));
  float sc = amax * (1.0f / 127.0f);
  if (tid == 0) s[row] = sc;
  int8_t* qr = q + (size_t)row * (2 * F_DIM);   // strided in-place rows
#pragma unroll
  for (int i = 0; i < 20; ++i) {
    int c = tid + i * 256;
    float qv = rintf(g[i] / sc);
    qv = fminf(fmaxf(qv, -127.f), 127.f);
    qr[c] = (int8_t)qv;
  }
}

// ============================================================================
// int8 GEMM, 256x256 tile, 8 waves, ring-of-4 K-tiles (BK=64), 16x16x64 MFMA.
// (conflict-free frag-read pattern; measured 0 LDS bank conflicts)
// ============================================================================
template <int MODE>
__global__ __launch_bounds__(512, 2) void gemm256_i8(
    const int8_t* __restrict__ A, const int8_t* __restrict__ B,
    const float* __restrict__ sx, const float* __restrict__ sw,
    const float* __restrict__ bias, const float* __restrict__ resid,
    void* __restrict__ outp, int M, int N, int K, int lda) {
  __shared__ __align__(16) int8_t As[2][2][256 * 64];
  __shared__ __align__(16) int8_t Bs[2][2][256 * 64];

  const int tid = threadIdx.x;
  const int lane = tid & 63;
  const int wave = tid >> 6;
  const int wm = wave >> 2;                       // 0..1  (M half)
  const int wn = wave & 3;                        // 0..3  (N quarter)
  const int l16 = lane & 15;
  const int quad = lane >> 4;
  const int choff = (quad ^ ((l16 >> 1) & 3)) << 4;   // read-side swizzled chunk

  // XCD-aware bijective swizzle (all grids divisible by 8)
  const int nwg = gridDim.x;
  const int ntn = N >> 8;
  const int u = (blockIdx.x & 7) * (nwg >> 3) + (blockIdx.x >> 3);
  const int tm = u / ntn, tn = u % ntn;
  const int m0 = tm << 8, n0 = tn << 8;

  const int8_t* A_blk = A + (size_t)m0 * lda;
  const int8_t* B_blk = B + (size_t)n0 * K;

  const int r0 = tid >> 2;                              // staged row (0..127)
  const int sch = ((tid & 3) ^ ((tid >> 3) & 3)) << 4;  // stage-side inv swizzle

#define STAGE_A(KT, DST)                                                         \
  {                                                                              \
    gload_lds16(A_blk + (size_t)r0 * lda + (size_t)(KT)*64 + sch,                \
                (DST) + tid * 16);                                               \
    gload_lds16(A_blk + (size_t)(r0 + 128) * lda + (size_t)(KT)*64 + sch,        \
                (DST) + 8192 + tid * 16);                                        \
  }
#define STAGE_B(KT, DST)                                                         \
  {                                                                              \
    gload_lds16(B_blk + (size_t)r0 * K + (size_t)(KT)*64 + sch,                  \
                (DST) + tid * 16);                                               \
    gload_lds16(B_blk + (size_t)(r0 + 128) * K + (size_t)(KT)*64 + sch,          \
                (DST) + 8192 + tid * 16);                                        \
  }

  v4i acc[8][4];
#pragma unroll
  for (int i = 0; i < 8; ++i)
#pragma unroll
    for (int j = 0; j < 4; ++j) acc[i][j] = (v4i){0, 0, 0, 0};

  const int nk = K >> 6;          // K-tiles of 64
  const int niter = nk >> 1;      // pairs of K-tiles

  // ---- prologue: stage tiles 0,1 into pair 0; wait tile 0 (oldest 4 of 8) ----
  STAGE_A(0, &As[0][0][0]); STAGE_B(0, &Bs[0][0][0]);
  STAGE_A(1, &As[0][1][0]); STAGE_B(1, &Bs[0][1][0]);
  asm volatile("s_waitcnt vmcnt(4)" ::: "memory");
  asm volatile("s_barrier" ::: "memory");

#pragma unroll 1
  for (int i = 0; i < niter - 1; ++i) {
    const int pr = i & 1;
    const int kt2 = 2 * i + 2;
#pragma unroll
    for (int ph = 0; ph < 4; ++ph) {
      const int tt = ph >> 1;     // tile within pair
      const int qm = ph & 1;      // M half of fragments
      const int8_t* At = &As[pr][tt][0];
      const int8_t* Bt = &Bs[pr][tt][0];
      v4i af[4], bf[4];
#pragma unroll
      for (int ii = 0; ii < 4; ++ii)
        af[ii] = *(const v4i*)(At + (wm * 128 + qm * 64 + ii * 16 + l16) * 64 + choff);
#pragma unroll
      for (int jj = 0; jj < 4; ++jj)
        bf[jj] = *(const v4i*)(Bt + (wn * 64 + jj * 16 + l16) * 64 + choff);
      // stage one half-matrix of the next pair's tile (2 loads)
      if (qm == 0) {
        STAGE_A(kt2 + tt, &As[pr ^ 1][tt][0]);
      } else {
        STAGE_B(kt2 + tt, &Bs[pr ^ 1][tt][0]);
      }
      asm volatile("s_barrier" ::: "memory");
      __builtin_amdgcn_s_setprio(1);
#pragma unroll
      for (int ii = 0; ii < 4; ++ii)
#pragma unroll
        for (int jj = 0; jj < 4; ++jj)
          acc[qm * 4 + ii][jj] = __builtin_amdgcn_mfma_i32_16x16x64_i8(
              af[ii], bf[jj], acc[qm * 4 + ii][jj], 0, 0, 0);
      __builtin_amdgcn_s_setprio(0);
      if (qm == 1) asm volatile("s_waitcnt vmcnt(4)" ::: "memory");
      asm volatile("s_barrier" ::: "memory");
    }
  }

  // ---- peeled final pair: no staging; drain remaining tile at phase 1 ----
  {
    const int pr = (niter - 1) & 1;
#pragma unroll
    for (int ph = 0; ph < 4; ++ph) {
      const int tt = ph >> 1;
      const int qm = ph & 1;
      const int8_t* At = &As[pr][tt][0];
      const int8_t* Bt = &Bs[pr][tt][0];
      v4i af[4], bf[4];
#pragma unroll
      for (int ii = 0; ii < 4; ++ii)
        af[ii] = *(const v4i*)(At + (wm * 128 + qm * 64 + ii * 16 + l16) * 64 + choff);
#pragma unroll
      for (int jj = 0; jj < 4; ++jj)
        bf[jj] = *(const v4i*)(Bt + (wn * 64 + jj * 16 + l16) * 64 + choff);
      asm volatile("s_barrier" ::: "memory");
      __builtin_amdgcn_s_setprio(1);
#pragma unroll
      for (int ii = 0; ii < 4; ++ii)
#pragma unroll
        for (int jj = 0; jj < 4; ++jj)
          acc[qm * 4 + ii][jj] = __builtin_amdgcn_mfma_i32_16x16x64_i8(
              af[ii], bf[jj], acc[qm * 4 + ii][jj], 0, 0, 0);
      __builtin_amdgcn_s_setprio(0);
      if (ph == 1) asm volatile("s_waitcnt vmcnt(0)" ::: "memory");
      asm volatile("s_barrier" ::: "memory");
    }
  }
#undef STAGE_A
#undef STAGE_B

  // ---- epilogue ----
  float swv[4], bv[4];
#pragma unroll
  for (int jj = 0; jj < 4; ++jj) {
    int n = n0 + wn * 64 + jj * 16 + l16;
    swv[jj] = sw[n];
    bv[jj] = bias[n];
  }
#pragma unroll
  for (int mf = 0; mf < 8; ++mf) {
#pragma unroll
    for (int r = 0; r < 4; ++r) {
      int m = m0 + wm * 128 + mf * 16 + quad * 4 + r;
      float sxm = sx[m];
#pragma unroll
      for (int jj = 0; jj < 4; ++jj) {
        int n = n0 + wn * 64 + jj * 16 + l16;
        float v = (float)acc[mf][jj][r] * (sxm * swv[jj]) + bv[jj];
        if constexpr (MODE == 0) {
          ((__hip_bfloat16*)outp)[(size_t)m * N + n] = __float2bfloat16(v);
        } else {
          ((float*)outp)[(size_t)m * N + n] = v + resid[(size_t)m * N + n];
        }
      }
    }
  }
}

// ============================================================================
// int8 GEMM, 128x128 tile, 4 waves, ring-of-4 K-tiles, 16x16x64 MFMA.
// 64 KiB LDS -> 2 blocks/CU; grid 1280 = 5 exact dispatch rounds.
// ============================================================================
template <int MODE>
__global__ __launch_bounds__(256, 2) void gemm128_i8(
    const int8_t* __restrict__ A, const int8_t* __restrict__ B,
    const float* __restrict__ sx, const float* __restrict__ sw,
    const float* __restrict__ bias, const float* __restrict__ resid,
    void* __restrict__ outp, int M, int N, int K, int lda) {
  __shared__ __align__(16) int8_t As[4][128 * 64];
  __shared__ __align__(16) int8_t Bs[4][128 * 64];

  const int tid = threadIdx.x;
  const int lane = tid & 63;
  const int wave = tid >> 6;
  const int wm = wave >> 1;                       // 0..1
  const int wn = wave & 1;                        // 0..1
  const int l16 = lane & 15;
  const int quad = lane >> 4;
  const int choff = (quad ^ ((l16 >> 1) & 3)) << 4;   // conflict-free pattern

  // XCD-aware bijective swizzle (grid divisible by 8)
  const int nwg = gridDim.x;
  const int ntn = N >> 7;
  const int u = (blockIdx.x & 7) * (nwg >> 3) + (blockIdx.x >> 3);
  const int tm = u / ntn, tn = u % ntn;
  const int m0 = tm << 7, n0 = tn << 7;

  const int8_t* A_blk = A + (size_t)m0 * lda;
  const int8_t* B_blk = B + (size_t)n0 * K;

  const int r0 = tid >> 2;                              // 0..63
  const int sch = ((tid & 3) ^ ((tid >> 3) & 3)) << 4;

#define STAGE_A(KT, SLOT)                                                        \
  {                                                                              \
    gload_lds16(A_blk + (size_t)r0 * lda + (size_t)(KT)*64 + sch,                \
                &As[SLOT][tid * 16]);                                            \
    gload_lds16(A_blk + (size_t)(r0 + 64) * lda + (size_t)(KT)*64 + sch,         \
                &As[SLOT][4096 + tid * 16]);                                     \
  }
#define STAGE_B(KT, SLOT)                                                        \
  {                                                                              \
    gload_lds16(B_blk + (size_t)r0 * K + (size_t)(KT)*64 + sch,                  \
                &Bs[SLOT][tid * 16]);                                            \
    gload_lds16(B_blk + (size_t)(r0 + 64) * K + (size_t)(KT)*64 + sch,           \
                &Bs[SLOT][4096 + tid * 16]);                                     \
  }

#define KTILE(SLOT, STAGE_STMT, WAIT_STMT)                                       \
  {                                                                              \
    const int8_t* At = &As[SLOT][0];                                             \
    const int8_t* Bt = &Bs[SLOT][0];                                             \
    v4i af[4], bf[4];                                                            \
    _Pragma("unroll") for (int ii = 0; ii < 4; ++ii)                             \
        af[ii] = *(const v4i*)(At + (wm * 64 + ii * 16 + l16) * 64 + choff);     \
    _Pragma("unroll") for (int jj = 0; jj < 4; ++jj)                             \
        bf[jj] = *(const v4i*)(Bt + (wn * 64 + jj * 16 + l16) * 64 + choff);     \
    STAGE_STMT;                                                                  \
    asm volatile("s_barrier" ::: "memory");                                      \
    __builtin_amdgcn_s_setprio(1);                                               \
    _Pragma("unroll") for (int ii = 0; ii < 4; ++ii)                             \
        _Pragma("unroll") for (int jj = 0; jj < 4; ++jj)                         \
            acc[ii][jj] = __builtin_amdgcn_mfma_i32_16x16x64_i8(                 \
                af[ii], bf[jj], acc[ii][jj], 0, 0, 0);                           \
    __builtin_amdgcn_s_setprio(0);                                               \
    WAIT_STMT;                                                                   \
    asm volatile("s_barrier" ::: "memory");                                      \
  }

  v4i acc[4][4];
#pragma unroll
  for (int i = 0; i < 4; ++i)
#pragma unroll
    for (int j = 0; j < 4; ++j) acc[i][j] = (v4i){0, 0, 0, 0};

  const int nk = K >> 6;          // >= 4 for all call sites

  // ---- prologue: stage tiles 0,1,2 (12 loads); wait tile 0 (oldest 4) ----
  STAGE_A(0, 0); STAGE_B(0, 0);
  STAGE_A(1, 1); STAGE_B(1, 1);
  STAGE_A(2, 2); STAGE_B(2, 2);
  asm volatile("s_waitcnt vmcnt(8)" ::: "memory");
  asm volatile("s_barrier" ::: "memory");

#pragma unroll 1
  for (int kt = 0; kt < nk - 3; ++kt) {
    const int sl = kt & 3;
    const int s3 = (kt + 3) & 3;
    KTILE(sl, { STAGE_A(kt + 3, s3); STAGE_B(kt + 3, s3); },
          asm volatile("s_waitcnt vmcnt(8)" ::: "memory"));
  }
  // ---- peel last 3 K-tiles (no staging; drain 8 -> 4 -> 0) ----
  KTILE((nk - 3) & 3, ((void)0), asm volatile("s_waitcnt vmcnt(4)" ::: "memory"));
  KTILE((nk - 2) & 3, ((void)0), asm volatile("s_waitcnt vmcnt(0)" ::: "memory"));
  KTILE((nk - 1) & 3, ((void)0), ((void)0));
#undef KTILE
#undef STAGE_A
#undef STAGE_B

  // ---- epilogue (16x16 C layout: col=lane&15, row=quad*4+r) ----
  float swv[4], bv[4];
#pragma unroll
  for (int jj = 0; jj < 4; ++jj) {
    int n = n0 + wn * 64 + jj * 16 + l16;
    swv[jj] = sw[n];
    bv[jj] = bias[n];
  }
#pragma unroll
  for (int ii = 0; ii < 4; ++ii) {
#pragma unroll
    for (int r = 0; r < 4; ++r) {
      int m = m0 + wm * 64 + ii * 16 + quad * 4 + r;
      float sxm = sx[m];
#pragma unroll
      for (int jj = 0; jj < 4; ++jj) {
        int n = n0 + wn * 64 + jj * 16 + l16;
        float v = (float)acc[ii][jj][r] * (sxm * swv[jj]) + bv[jj];
        if constexpr (MODE == 0) {
          ((__hip_bfloat16*)outp)[(size_t)m * N + n] = __float2bfloat16(v);
        } else {
          ((float*)outp)[(size_t)m * N + n] = v + resid[(size_t)m * N + n];
        }
      }
    }
  }
}

// ---------- V transpose: Vt[bh][d][k] = V[b,k,h,d] ----------
__global__ __launch_bounds__(256) void vt_kernel(
    const __hip_bfloat16* __restrict__ qkv, __hip_bfloat16* __restrict__ Vt) {
  __shared__ __hip_bfloat16 tile[64][72];
  const int bh = blockIdx.y, kc = blockIdx.x;
  const int b = bh / NH, h = bh % NH;
  const int tid = threadIdx.x;
  const size_t base = ((size_t)b * S_LEN + (size_t)kc * 64) * (3 * E_DIM) + 2 * E_DIM + h * 64;
#pragma unroll
  for (int i = 0; i < 2; ++i) {
    int idx = tid + i * 256;
    int row = idx >> 3, c8 = (idx & 7) * 8;
    *(uint4*)&tile[row][c8] = *(const uint4*)(qkv + base + (size_t)row * (3 * E_DIM) + c8);
  }
  __syncthreads();
#pragma unroll
  for (int i = 0; i < 2; ++i) {
    int idx = tid + i * 256;
    int d = idx >> 3, k8 = (idx & 7) * 8;
    __hip_bfloat16 v[8] __attribute__((aligned(16)));
#pragma unroll
    for (int j = 0; j < 8; ++j) v[j] = tile[k8 + j][d];
    *(uint4*)&Vt[((size_t)bh * 64 + d) * 1024 + (size_t)kc * 64 + k8] = *(uint4*)v;
  }
}

// ---------- flash MFMA attention: r3-exact + quarter-P (GEMM-proven swizzle) ----------
// Quarter-P v2: Ps rows are 64B (4 chunks of 16B), stored chunk = logical ^
// ((l16>>1)&3) — the exact swizzle geometry that measured 0 bank conflicts in
// the GEMM frag reads (slot index 4*l16+chunk mod 8 covers all 8 groups over
// consecutive lanes). LDS = 37.1KB -> 4 blocks/CU (16 waves/CU).
__global__ __launch_bounds__(256, 4) void attn_flash_kernel(
    const __hip_bfloat16* __restrict__ qkv, const __hip_bfloat16* __restrict__ Vt,
    __hip_bfloat16* __restrict__ attn) {
  constexpr int E3 = 3 * E_DIM;
  __shared__ __align__(16) __hip_bfloat16 Ks[128 * 64];   // [row][8 chunks, ^(row&7)]
  __shared__ __align__(16) __hip_bfloat16 Vs[64 * 128];   // [d][16 chunks, ^(d&15)]
  __shared__ __align__(16) __hip_bfloat16 Ps[4][16 * 32]; // quarter-P, 64B rows
  __shared__ float stats[4][16];

  const int tid = threadIdx.x;
  const int lane = tid & 63;
  const int wave = tid >> 6;
  const int l16 = lane & 15;
  const int quad = lane >> 4;
  const int bh = blockIdx.y;
  const int b = bh / NH, h = bh % NH;
  const int q0 = blockIdx.x * 64;
  const size_t base_t = (size_t)b * S_LEN;

  // Q B-fragments for this wave's 16 q-rows
  v8s qb0, qb1;
  {
    const __hip_bfloat16* qp =
        qkv + (base_t + q0 + wave * 16 + l16) * (size_t)E3 + h * 64 + quad * 8;
    qb0 = *(const v8s*)qp;
    qb1 = *(const v8s*)(qp + 32);
  }

  float m_prev = -3.0e38f;
  float lsum = 0.f;
  v4f oc[4];
#pragma unroll
  for (int dt = 0; dt < 4; ++dt) oc[dt] = (v4f){0.f, 0.f, 0.f, 0.f};

  const __hip_bfloat16* kgbase = qkv + base_t * E3 + E_DIM + h * 64;
  const __hip_bfloat16* vgbase = Vt + (size_t)bh * 64 * 1024;
  char* pw = (char*)Ps[wave];
  const int pswz = (l16 >> 1) & 3;               // GEMM-proven P swizzle

#pragma unroll 1
  for (int t = 0; t < 8; ++t) {
    __syncthreads();  // all waves done reading previous Ks/Vs tile
#pragma unroll
    for (int i = 0; i < 4; ++i) {   // stage K tile: 128 rows x 128B
      int c = tid + i * 256;
      int row = c >> 3, lc = c & 7;
      int gc = lc ^ (row & 7);
      gload_lds16(kgbase + (size_t)(t * 128 + row) * E3 + gc * 8, (char*)Ks + c * 16);
    }
#pragma unroll
    for (int i = 0; i < 4; ++i) {   // stage V tile: 64 d x 256B
      int c = tid + i * 256;
      int d = c >> 4, lc = c & 15;
      int gc = lc ^ (d & 15);
      gload_lds16(vgbase + (size_t)d * 1024 + t * 128 + gc * 8, (char*)Vs + c * 16);
    }
    __syncthreads();  // staged (vmcnt drained by barrier semantics)

    // ---- scores^T: D[kc][q] ; 8 kc-tiles of 16 ----
    v4f accT[8];
#pragma unroll
    for (int nt = 0; nt < 8; ++nt) {
      int row = nt * 16 + l16;
      const char* kr = (const char*)Ks + row * 128;
      v8s ak0 = *(const v8s*)(kr + ((quad ^ (row & 7)) * 16));
      v8s ak1 = *(const v8s*)(kr + (((quad + 4) ^ (row & 7)) * 16));
      v4f z = {0.f, 0.f, 0.f, 0.f};
      z = __builtin_amdgcn_mfma_f32_16x16x32_bf16(ak0, qb0, z, 0, 0, 0);
      accT[nt] = __builtin_amdgcn_mfma_f32_16x16x32_bf16(ak1, qb1, accT[nt] = z, 0, 0, 0);
    }

    // ---- online softmax (per-lane q = l16; quads hold disjoint k-slices) ----
    float mt = -3.0e38f;
#pragma unroll
    for (int nt = 0; nt < 8; ++nt)
#pragma unroll
      for (int r = 0; r < 4; ++r) mt = fmaxf(mt, accT[nt][r]);
    mt = fmaxf(mt, __shfl_xor(mt, 16, 64));
    mt = fmaxf(mt, __shfl_xor(mt, 32, 64));
    float m_new = fmaxf(m_prev, mt);
    float alpha = __expf(0.125f * (m_prev - m_new));
    m_prev = m_new;
    float ts = 0.f;
#pragma unroll
    for (int nt = 0; nt < 8; ++nt)
#pragma unroll
      for (int r = 0; r < 4; ++r) {
        float e = __expf(0.125f * (accT[nt][r] - m_new));
        accT[nt][r] = e;
        ts += e;
      }
    lsum = lsum * alpha + ts;
    if (quad == 0) stats[wave][l16] = alpha;
    // rescale O (alpha for q=quad*4+r via LDS; same-wave DS ops are in-order)
    v4f a4 = *(v4f*)&stats[wave][quad * 4];
#pragma unroll
    for (int dt = 0; dt < 4; ++dt)
#pragma unroll
      for (int r = 0; r < 4; ++r) oc[dt][r] *= a4[r];

    // ---- PV in 4 k-32 blocks; quarter-P staged per block ----
    // write: lane(q=l16,quad) holds S[k=nt*16+quad*4+r][q]; block j, nt=2j+e2
    //   -> k_local = e2*16+quad*4+r -> logical chunk 2*e2+(quad>>1), half quad&1.
    // read: A-frag P[q][quad*8..+7] = logical chunk quad.
    // Both sides store chunk ^ pswz (GEMM zero-conflict geometry, 64B rows).
#pragma unroll
    for (int j = 0; j < 4; ++j) {
#pragma unroll
      for (int e2 = 0; e2 < 2; ++e2) {
        int nt = 2 * j + e2;
        __hip_bfloat16 pk[4] __attribute__((aligned(8)));
#pragma unroll
        for (int r = 0; r < 4; ++r) pk[r] = __float2bfloat16(accT[nt][r]);
        int lcw = 2 * e2 + (quad >> 1);
        *(uint2*)(pw + l16 * 64 + ((lcw ^ pswz) * 16) + (quad & 1) * 8) = *(uint2*)pk;
      }
      v8s ap = *(const v8s*)(pw + l16 * 64 + ((quad ^ pswz) * 16));
#pragma unroll
      for (int dt = 0; dt < 4; ++dt) {
        int d = dt * 16 + l16;
        v8s bv = *(const v8s*)((char*)Vs + d * 256 + (((j * 4 + quad) ^ l16) * 16));
        oc[dt] = __builtin_amdgcn_mfma_f32_16x16x32_bf16(ap, bv, oc[dt], 0, 0, 0);
      }
    }
  }

  // ---- epilogue: finish l, normalize, store ----
  lsum += __shfl_xor(lsum, 16, 64);
  lsum += __shfl_xor(lsum, 32, 64);
  if (quad == 0) stats[wave][l16] = lsum;
  v4f l4 = *(v4f*)&stats[wave][quad * 4];
  float inv[4];
#pragma unroll
  for (int r = 0; r < 4; ++r) inv[r] = 1.0f / l4[r];
#pragma unroll
  for (int dt = 0; dt < 4; ++dt)
#pragma unroll
    for (int r = 0; r < 4; ++r) {
      int tok = q0 + wave * 16 + quad * 4 + r;
      attn[(base_t + tok) * (size_t)E_DIM + h * 64 + dt * 16 + l16] =
          __float2bfloat16(oc[dt][r] * inv[r]);
    }
}

// ---------- launch ----------
extern "C" void kernel_launch(void* const* d_in, const int* in_sizes, int n_in,
                              void* d_out, int out_size, void* d_ws, size_t ws_size,
                              hipStream_t stream) {
  const float* hidden = (const float*)d_in[0];
  const float* ln1_w = (const float*)d_in[1];
  const float* ln1_b = (const float*)d_in[2];
  const float* ln2_w = (const float*)d_in[3];
  const float* ln2_b = (const float*)d_in[4];
  const float* W_qkv = (const float*)d_in[5];
  const float* b_qkv = (const float*)d_in[6];
  const float* W_out = (const float*)d_in[7];
  const float* b_out = (const float*)d_in[8];
  const float* W_fc1 = (const float*)d_in[9];
  const float* b_fc1 = (const float*)d_in[10];
  const float* W_fc2 = (const float*)d_in[11];
  const float* b_fc2 = (const float*)d_in[12];

  // ---- workspace plan (~250.7 MB) ----
  char* ws = (char*)d_ws;
  size_t off = 0;
  auto alloc = [&](size_t bytes) {
    void* p = ws + off;
    off += (bytes + 255) & ~(size_t)255;
    return p;
  };
  int8_t* qw_qkv = (int8_t*)alloc((size_t)3 * E_DIM * E_DIM);
  int8_t* qw_out = (int8_t*)alloc((size_t)E_DIM * E_DIM);
  int8_t* qw_fc1 = (int8_t*)alloc((size_t)F_DIM * E_DIM);
  int8_t* qw_fc2 = (int8_t*)alloc((size_t)E_DIM * F_DIM);
  float* sw_qkv = (float*)alloc((size_t)3 * E_DIM * 4);
  float* sw_out = (float*)alloc((size_t)E_DIM * 4);
  float* sw_fc1 = (float*)alloc((size_t)F_DIM * 4);
  float* sw_fc2 = (float*)alloc((size_t)E_DIM * 4);
  float* sx1 = (float*)alloc((size_t)T_DIM * 4);
  float* sa  = (float*)alloc((size_t)T_DIM * 4);
  float* sx2 = (float*)alloc((size_t)T_DIM * 4);
  float* sg  = (float*)alloc((size_t)T_DIM * 4);
  int8_t* qx = (int8_t*)alloc((size_t)T_DIM * E_DIM);              // reused 3x
  char* R = (char*)alloc((size_t)T_DIM * 3 * E_DIM * 2 +           // 209,715,200 B
                         (size_t)T_DIM * E_DIM * 4);
  __hip_bfloat16* qkv_bf = (__hip_bfloat16*)R;
  __hip_bfloat16* attn_bf = (__hip_bfloat16*)(R + (size_t)T_DIM * 3 * E_DIM * 2);
  __hip_bfloat16* Vt = (__hip_bfloat16*)(R + (size_t)T_DIM * 3 * E_DIM * 2 +
                                         (size_t)T_DIM * E_DIM * 2);
  __hip_bfloat16* f1_bf = (__hip_bfloat16*)R;
  int8_t* qg = (int8_t*)R;                                         // strided lda=2F
  float* hidden2 = (float*)d_out;

  // 1) weight quantization
  wquant_kernel<<<3 * E_DIM, 256, 0, stream>>>(W_qkv, qw_qkv, sw_qkv, E_DIM);
  wquant_kernel<<<E_DIM, 256, 0, stream>>>(W_out, qw_out, sw_out, E_DIM);
  wquant_kernel<<<F_DIM, 256, 0, stream>>>(W_fc1, qw_fc1, sw_fc1, E_DIM);
  wquant_kernel<<<E_DIM, 256, 0, stream>>>(W_fc2, qw_fc2, sw_fc2, F_DIM);
  // 2) rms1 + quant
  rms_quant_kernel<<<T_DIM, 256, 0, stream>>>(hidden, ln1_w, ln1_b, qx, sx1);
  // 3) QKV gemm -> bf16   (grid = 64 * 15 = 960 blocks)
  gemm256_i8<0><<<(T_DIM / 256) * (3 * E_DIM / 256), 512, 0, stream>>>(
      qx, qw_qkv, sx1, sw_qkv, b_qkv, nullptr, qkv_bf, T_DIM, 3 * E_DIM, E_DIM, E_DIM);
  // 4) V transpose
  vt_kernel<<<dim3(S_LEN / 64, B_SZ * NH), 256, 0, stream>>>(qkv_bf, Vt);
  // 5) flash MFMA attention -> bf16  (r3 grid; 4 blocks/CU)
  attn_flash_kernel<<<dim3(S_LEN / 64, B_SZ * NH), 256, 0, stream>>>(qkv_bf, Vt, attn_bf);
  // 6) quant attn
  row_quant_bf_kernel<<<T_DIM, 256, 0, stream>>>(attn_bf, qx, sa);
  // 7) out proj + residual -> hidden2 (= d_out)  (grid = 128 * 10 = 1280)
  gemm128_i8<1><<<(T_DIM / 128) * (E_DIM / 128), 256, 0, stream>>>(
      qx, qw_out, sa, sw_out, b_out, hidden, hidden2, T_DIM, E_DIM, E_DIM, E_DIM);
  // 8) rms2 + quant
  rms_quant_kernel<<<T_DIM, 256, 0, stream>>>(hidden2, ln2_w, ln2_b, qx, sx2);
  // 9) FC1 gemm -> bf16   (grid = 64 * 20 = 1280)
  gemm256_i8<0><<<(T_DIM / 256) * (F_DIM / 256), 512, 0, stream>>>(
      qx, qw_fc1, sx2, sw_fc1, b_fc1, nullptr, f1_bf, T_DIM, F_DIM, E_DIM, E_DIM);
  // 10) gelu + quant (in-place strided int8 rows inside f1 buffer)
  gelu_quant_kernel<<<T_DIM, 256, 0, stream>>>(f1_bf, qg, sg);
  // 11) FC2 gemm + residual -> d_out (in-place, element-private)
  gemm128_i8<1><<<(T_DIM / 128) * (E_DIM / 128), 256, 0, stream>>>(
      qg, qw_fc2, sg, sw_fc2, b_fc2, hidden2, (float*)d_out, T_DIM, E_DIM, F_DIM, 2 * F_DIM);
}

// Round 9
// 1029.925 us; speedup vs baseline: 1.0269x; 1.0016x over previous
//
#include <hip/hip_runtime.h>
#include <hip/hip_bf16.h>
#include <stdint.h>

#define E_DIM 1280
#define F_DIM 5120
#define T_DIM 16384
#define B_SZ  16
#define S_LEN 1024
#define NH    20

typedef int v4i __attribute__((ext_vector_type(4)));
typedef __attribute__((ext_vector_type(8))) short v8s;
typedef __attribute__((ext_vector_type(4))) float v4f;

// ---------- helpers ----------
__device__ __forceinline__ float wred_sum(float v) {
#pragma unroll
  for (int m = 32; m > 0; m >>= 1) v += __shfl_xor(v, m, 64);
  return v;
}
__device__ __forceinline__ float wred_max(float v) {
#pragma unroll
  for (int m = 32; m > 0; m >>= 1) v = fmaxf(v, __shfl_xor(v, m, 64));
  return v;
}
__device__ __forceinline__ void gload_lds16(const void* g, void* l) {
  __builtin_amdgcn_global_load_lds((const __attribute__((address_space(1))) void*)g,
                                   (__attribute__((address_space(3))) void*)l, 16, 0, 0);
}

// ---------- per-output-channel weight quant ----------
__global__ __launch_bounds__(256) void wquant_kernel(
    const float* __restrict__ W, int8_t* __restrict__ qw, float* __restrict__ sw, int K) {
  __shared__ float red[4];
  const int row = blockIdx.x;
  const int tid = threadIdx.x;
  const float* wr = W + (size_t)row * K;
  float amax = 0.f;
  for (int c = tid; c < K; c += 256) amax = fmaxf(amax, fabsf(wr[c]));
  amax = wred_max(amax);
  if ((tid & 63) == 0) red[tid >> 6] = amax;
  __syncthreads();
  amax = fmaxf(fmaxf(red[0], red[1]), fmaxf(red[2], red[3]));
  float sc = amax * (1.0f / 127.0f);
  if (tid == 0) sw[row] = sc;
  for (int c = tid; c < K; c += 256) {
    float qv = rintf(wr[c] / sc);
    qw[(size_t)row * K + c] = (int8_t)qv;
  }
}

// ---------- RMSNorm(+bias) + per-token quant (E=1280) ----------
__global__ __launch_bounds__(256) void rms_quant_kernel(
    const float* __restrict__ x, const float* __restrict__ w, const float* __restrict__ b,
    int8_t* __restrict__ q, float* __restrict__ s) {
  __shared__ float red[4];
  const int row = blockIdx.x;
  const int tid = threadIdx.x;
  const float* xr = x + (size_t)row * E_DIM;
  float vals[5];
  float ss = 0.f;
#pragma unroll
  for (int i = 0; i < 5; ++i) {
    float v = xr[tid + i * 256];
    vals[i] = v; ss += v * v;
  }
  ss = wred_sum(ss);
  if ((tid & 63) == 0) red[tid >> 6] = ss;
  __syncthreads();
  ss = red[0] + red[1] + red[2] + red[3];
  float rstd = rsqrtf(ss * (1.0f / E_DIM) + 1e-6f);
  float y[5]; float amax = 0.f;
#pragma unroll
  for (int i = 0; i < 5; ++i) {
    int c = tid + i * 256;
    float v = vals[i] * rstd * w[c] + b[c];
    y[i] = v;
    amax = fmaxf(amax, fabsf(v));
  }
  amax = wred_max(amax);
  __syncthreads();
  if ((tid & 63) == 0) red[tid >> 6] = amax;
  __syncthreads();
  amax = fmaxf(fmaxf(red[0], red[1]), fmaxf(red[2], red[3]));
  float sc = amax * (1.0f / 127.0f);
  if (tid == 0) s[row] = sc;
#pragma unroll
  for (int i = 0; i < 5; ++i) {
    int c = tid + i * 256;
    float qv = rintf(y[i] / sc);
    qv = fminf(fmaxf(qv, -127.f), 127.f);
    q[(size_t)row * E_DIM + c] = (int8_t)qv;
  }
}

// ---------- per-token quant (E=1280, bf16 in) ----------
__global__ __launch_bounds__(256) void row_quant_bf_kernel(
    const __hip_bfloat16* __restrict__ x, int8_t* __restrict__ q, float* __restrict__ s) {
  __shared__ float red[4];
  const int row = blockIdx.x;
  const int tid = threadIdx.x;
  const __hip_bfloat16* xr = x + (size_t)row * E_DIM;
  float vals[5]; float amax = 0.f;
#pragma unroll
  for (int i = 0; i < 5; ++i) {
    float v = __bfloat162float(xr[tid + i * 256]);
    vals[i] = v;
    amax = fmaxf(amax, fabsf(v));
  }
  amax = wred_max(amax);
  if ((tid & 63) == 0) red[tid >> 6] = amax;
  __syncthreads();
  amax = fmaxf(fmaxf(red[0], red[1]), fmaxf(red[2], red[3]));
  float sc = amax * (1.0f / 127.0f);
  if (tid == 0) s[row] = sc;
#pragma unroll
  for (int i = 0; i < 5; ++i) {
    int c = tid + i * 256;
    float qv = rintf(vals[i] / sc);
    qv = fminf(fmaxf(qv, -127.f), 127.f);
    q[(size_t)row * E_DIM + c] = (int8_t)qv;
  }
}

// ---------- exact GELU + per-token quant (F=5120, bf16 in, int8 in-place) ----------
__global__ __launch_bounds__(256) void gelu_quant_kernel(
    const __hip_bfloat16* __restrict__ f1, int8_t* __restrict__ q, float* __restrict__ s) {
  __shared__ float red[4];
  const int row = blockIdx.x;
  const int tid = threadIdx.x;
  const __hip_bfloat16* xr = f1 + (size_t)row * F_DIM;
  float g[20]; float amax = 0.f;
#pragma unroll
  for (int i = 0; i < 20; ++i) {
    float v = __bfloat162float(xr[tid + i * 256]);
    float gv = 0.5f * v * (1.0f + erff(v * 0.70710678118654752440f));
    g[i] = gv;
    amax = fmaxf(amax, fabsf(gv));
  }
  amax = wred_max(amax);
  if ((tid & 63) == 0) red[tid >> 6] = amax;
  __syncthreads();
  amax = fmaxf(fmaxf(red[0], red[1]), fmaxf(red[2], red[3]));
  float sc = amax * (1.0f / 127.0f);
  if (tid == 0) s[row] = sc;
  int8_t* qr = q + (size_t)row * (2 * F_DIM);   // strided in-place rows
#pragma unroll
  for (int i = 0; i < 20; ++i) {
    int c = tid + i * 256;
    float qv = rintf(g[i] / sc);
    qv = fminf(fmaxf(qv, -127.f), 127.f);
    qr[c] = (int8_t)qv;
  }
}

// ============================================================================
// int8 GEMM, 256x256 tile, 8 waves, ring-of-4 K-tiles (BK=64), 16x16x64 MFMA.
// (conflict-free frag-read pattern; measured 0 LDS bank conflicts)
// ============================================================================
template <int MODE>
__global__ __launch_bounds__(512, 2) void gemm256_i8(
    const int8_t* __restrict__ A, const int8_t* __restrict__ B,
    const float* __restrict__ sx, const float* __restrict__ sw,
    const float* __restrict__ bias, const float* __restrict__ resid,
    void* __restrict__ outp, int M, int N, int K, int lda) {
  __shared__ __align__(16) int8_t As[2][2][256 * 64];
  __shared__ __align__(16) int8_t Bs[2][2][256 * 64];

  const int tid = threadIdx.x;
  const int lane = tid & 63;
  const int wave = tid >> 6;
  const int wm = wave >> 2;                       // 0..1  (M half)
  const int wn = wave & 3;                        // 0..3  (N quarter)
  const int l16 = lane & 15;
  const int quad = lane >> 4;
  const int choff = (quad ^ ((l16 >> 1) & 3)) << 4;   // read-side swizzled chunk

  // XCD-aware bijective swizzle (all grids divisible by 8)
  const int nwg = gridDim.x;
  const int ntn = N >> 8;
  const int u = (blockIdx.x & 7) * (nwg >> 3) + (blockIdx.x >> 3);
  const int tm = u / ntn, tn = u % ntn;
  const int m0 = tm << 8, n0 = tn << 8;

  const int8_t* A_blk = A + (size_t)m0 * lda;
  const int8_t* B_blk = B + (size_t)n0 * K;

  const int r0 = tid >> 2;                              // staged row (0..127)
  const int sch = ((tid & 3) ^ ((tid >> 3) & 3)) << 4;  // stage-side inv swizzle

#define STAGE_A(KT, DST)                                                         \
  {                                                                              \
    gload_lds16(A_blk + (size_t)r0 * lda + (size_t)(KT)*64 + sch,                \
                (DST) + tid * 16);                                               \
    gload_lds16(A_blk + (size_t)(r0 + 128) * lda + (size_t)(KT)*64 + sch,        \
                (DST) + 8192 + tid * 16);                                        \
  }
#define STAGE_B(KT, DST)                                                         \
  {                                                                              \
    gload_lds16(B_blk + (size_t)r0 * K + (size_t)(KT)*64 + sch,                  \
                (DST) + tid * 16);                                               \
    gload_lds16(B_blk + (size_t)(r0 + 128) * K + (size_t)(KT)*64 + sch,          \
                (DST) + 8192 + tid * 16);                                        \
  }

  v4i acc[8][4];
#pragma unroll
  for (int i = 0; i < 8; ++i)
#pragma unroll
    for (int j = 0; j < 4; ++j) acc[i][j] = (v4i){0, 0, 0, 0};

  const int nk = K >> 6;          // K-tiles of 64
  const int niter = nk >> 1;      // pairs of K-tiles

  // ---- prologue: stage tiles 0,1 into pair 0; wait tile 0 (oldest 4 of 8) ----
  STAGE_A(0, &As[0][0][0]); STAGE_B(0, &Bs[0][0][0]);
  STAGE_A(1, &As[0][1][0]); STAGE_B(1, &Bs[0][1][0]);
  asm volatile("s_waitcnt vmcnt(4)" ::: "memory");
  asm volatile("s_barrier" ::: "memory");

#pragma unroll 1
  for (int i = 0; i < niter - 1; ++i) {
    const int pr = i & 1;
    const int kt2 = 2 * i + 2;
#pragma unroll
    for (int ph = 0; ph < 4; ++ph) {
      const int tt = ph >> 1;     // tile within pair
      const int qm = ph & 1;      // M half of fragments
      const int8_t* At = &As[pr][tt][0];
      const int8_t* Bt = &Bs[pr][tt][0];
      v4i af[4], bf[4];
#pragma unroll
      for (int ii = 0; ii < 4; ++ii)
        af[ii] = *(const v4i*)(At + (wm * 128 + qm * 64 + ii * 16 + l16) * 64 + choff);
#pragma unroll
      for (int jj = 0; jj < 4; ++jj)
        bf[jj] = *(const v4i*)(Bt + (wn * 64 + jj * 16 + l16) * 64 + choff);
      // stage one half-matrix of the next pair's tile (2 loads)
      if (qm == 0) {
        STAGE_A(kt2 + tt, &As[pr ^ 1][tt][0]);
      } else {
        STAGE_B(kt2 + tt, &Bs[pr ^ 1][tt][0]);
      }
      asm volatile("s_barrier" ::: "memory");
      __builtin_amdgcn_s_setprio(1);
#pragma unroll
      for (int ii = 0; ii < 4; ++ii)
#pragma unroll
        for (int jj = 0; jj < 4; ++jj)
          acc[qm * 4 + ii][jj] = __builtin_amdgcn_mfma_i32_16x16x64_i8(
              af[ii], bf[jj], acc[qm * 4 + ii][jj], 0, 0, 0);
      __builtin_amdgcn_s_setprio(0);
      if (qm == 1) asm volatile("s_waitcnt vmcnt(4)" ::: "memory");
      asm volatile("s_barrier" ::: "memory");
    }
  }

  // ---- peeled final pair: no staging; drain remaining tile at phase 1 ----
  {
    const int pr = (niter - 1) & 1;
#pragma unroll
    for (int ph = 0; ph < 4; ++ph) {
      const int tt = ph >> 1;
      const int qm = ph & 1;
      const int8_t* At = &As[pr][tt][0];
      const int8_t* Bt = &Bs[pr][tt][0];
      v4i af[4], bf[4];
#pragma unroll
      for (int ii = 0; ii < 4; ++ii)
        af[ii] = *(const v4i*)(At + (wm * 128 + qm * 64 + ii * 16 + l16) * 64 + choff);
#pragma unroll
      for (int jj = 0; jj < 4; ++jj)
        bf[jj] = *(const v4i*)(Bt + (wn * 64 + jj * 16 + l16) * 64 + choff);
      asm volatile("s_barrier" ::: "memory");
      __builtin_amdgcn_s_setprio(1);
#pragma unroll
      for (int ii = 0; ii < 4; ++ii)
#pragma unroll
        for (int jj = 0; jj < 4; ++jj)
          acc[qm * 4 + ii][jj] = __builtin_amdgcn_mfma_i32_16x16x64_i8(
              af[ii], bf[jj], acc[qm * 4 + ii][jj], 0, 0, 0);
      __builtin_amdgcn_s_setprio(0);
      if (ph == 1) asm volatile("s_waitcnt vmcnt(0)" ::: "memory");
      asm volatile("s_barrier" ::: "memory");
    }
  }
#undef STAGE_A
#undef STAGE_B

  // ---- epilogue ----
  float swv[4], bv[4];
#pragma unroll
  for (int jj = 0; jj < 4; ++jj) {
    int n = n0 + wn * 64 + jj * 16 + l16;
    swv[jj] = sw[n];
    bv[jj] = bias[n];
  }
#pragma unroll
  for (int mf = 0; mf < 8; ++mf) {
#pragma unroll
    for (int r = 0; r < 4; ++r) {
      int m = m0 + wm * 128 + mf * 16 + quad * 4 + r;
      float sxm = sx[m];
#pragma unroll
      for (int jj = 0; jj < 4; ++jj) {
        int n = n0 + wn * 64 + jj * 16 + l16;
        float v = (float)acc[mf][jj][r] * (sxm * swv[jj]) + bv[jj];
        if constexpr (MODE == 0) {
          ((__hip_bfloat16*)outp)[(size_t)m * N + n] = __float2bfloat16(v);
        } else {
          ((float*)outp)[(size_t)m * N + n] = v + resid[(size_t)m * N + n];
        }
      }
    }
  }
}

// ============================================================================
// int8 GEMM, 128x128 tile, 4 waves, ring-of-3 K-tiles, 16x16x64 MFMA.
// 48 KiB LDS -> 3 blocks/CU (12 waves/CU) for latency hiding.
// Ring-3 invariants: prologue stages tiles 0,1 (8 loads), vmcnt(4) retires
// tile 0. Steady state: read tile kt, stage kt+2 (outstanding 8), MFMA,
// vmcnt(4) retires kt+1. Peel last 2 tiles draining 4 -> 0.
// ============================================================================
template <int MODE>
__global__ __launch_bounds__(256, 3) void gemm128_i8(
    const int8_t* __restrict__ A, const int8_t* __restrict__ B,
    const float* __restrict__ sx, const float* __restrict__ sw,
    const float* __restrict__ bias, const float* __restrict__ resid,
    void* __restrict__ outp, int M, int N, int K, int lda) {
  __shared__ __align__(16) int8_t As[3][128 * 64];
  __shared__ __align__(16) int8_t Bs[3][128 * 64];

  const int tid = threadIdx.x;
  const int lane = tid & 63;
  const int wave = tid >> 6;
  const int wm = wave >> 1;                       // 0..1
  const int wn = wave & 1;                        // 0..1
  const int l16 = lane & 15;
  const int quad = lane >> 4;
  const int choff = (quad ^ ((l16 >> 1) & 3)) << 4;   // conflict-free pattern

  // XCD-aware bijective swizzle (grid divisible by 8)
  const int nwg = gridDim.x;
  const int ntn = N >> 7;
  const int u = (blockIdx.x & 7) * (nwg >> 3) + (blockIdx.x >> 3);
  const int tm = u / ntn, tn = u % ntn;
  const int m0 = tm << 7, n0 = tn << 7;

  const int8_t* A_blk = A + (size_t)m0 * lda;
  const int8_t* B_blk = B + (size_t)n0 * K;

  const int r0 = tid >> 2;                              // 0..63
  const int sch = ((tid & 3) ^ ((tid >> 3) & 3)) << 4;

#define STAGE_A(KT, SLOT)                                                        \
  {                                                                              \
    gload_lds16(A_blk + (size_t)r0 * lda + (size_t)(KT)*64 + sch,                \
                &As[SLOT][tid * 16]);                                            \
    gload_lds16(A_blk + (size_t)(r0 + 64) * lda + (size_t)(KT)*64 + sch,         \
                &As[SLOT][4096 + tid * 16]);                                     \
  }
#define STAGE_B(KT, SLOT)                                                        \
  {                                                                              \
    gload_lds16(B_blk + (size_t)r0 * K + (size_t)(KT)*64 + sch,                  \
                &Bs[SLOT][tid * 16]);                                            \
    gload_lds16(B_blk + (size_t)(r0 + 64) * K + (size_t)(KT)*64 + sch,           \
                &Bs[SLOT][4096 + tid * 16]);                                     \
  }

#define KTILE(SLOT, STAGE_STMT, WAIT_STMT)                                       \
  {                                                                              \
    const int8_t* At = &As[SLOT][0];                                             \
    const int8_t* Bt = &Bs[SLOT][0];                                             \
    v4i af[4], bf[4];                                                            \
    _Pragma("unroll") for (int ii = 0; ii < 4; ++ii)                             \
        af[ii] = *(const v4i*)(At + (wm * 64 + ii * 16 + l16) * 64 + choff);     \
    _Pragma("unroll") for (int jj = 0; jj < 4; ++jj)                             \
        bf[jj] = *(const v4i*)(Bt + (wn * 64 + jj * 16 + l16) * 64 + choff);     \
    STAGE_STMT;                                                                  \
    asm volatile("s_barrier" ::: "memory");                                      \
    __builtin_amdgcn_s_setprio(1);                                               \
    _Pragma("unroll") for (int ii = 0; ii < 4; ++ii)                             \
        _Pragma("unroll") for (int jj = 0; jj < 4; ++jj)                         \
            acc[ii][jj] = __builtin_amdgcn_mfma_i32_16x16x64_i8(                 \
                af[ii], bf[jj], acc[ii][jj], 0, 0, 0);                           \
    __builtin_amdgcn_s_setprio(0);                                               \
    WAIT_STMT;                                                                   \
    asm volatile("s_barrier" ::: "memory");                                      \
  }

  v4i acc[4][4];
#pragma unroll
  for (int i = 0; i < 4; ++i)
#pragma unroll
    for (int j = 0; j < 4; ++j) acc[i][j] = (v4i){0, 0, 0, 0};

  const int nk = K >> 6;          // >= 20 for all call sites

  // ---- prologue: stage tiles 0,1 (8 loads); wait tile 0 (oldest 4) ----
  STAGE_A(0, 0); STAGE_B(0, 0);
  STAGE_A(1, 1); STAGE_B(1, 1);
  asm volatile("s_waitcnt vmcnt(4)" ::: "memory");
  asm volatile("s_barrier" ::: "memory");

#pragma unroll 1
  for (int kt = 0; kt < nk - 2; ++kt) {
    const int sl = kt % 3;
    const int s2 = (kt + 2) % 3;
    KTILE(sl, { STAGE_A(kt + 2, s2); STAGE_B(kt + 2, s2); },
          asm volatile("s_waitcnt vmcnt(4)" ::: "memory"));
  }
  // ---- peel last 2 K-tiles (no staging; drain 4 -> 0) ----
  KTILE((nk - 2) % 3, ((void)0), asm volatile("s_waitcnt vmcnt(0)" ::: "memory"));
  KTILE((nk - 1) % 3, ((void)0), ((void)0));
#undef KTILE
#undef STAGE_A
#undef STAGE_B

  // ---- epilogue (16x16 C layout: col=lane&15, row=quad*4+r) ----
  float swv[4], bv[4];
#pragma unroll
  for (int jj = 0; jj < 4; ++jj) {
    int n = n0 + wn * 64 + jj * 16 + l16;
    swv[jj] = sw[n];
    bv[jj] = bias[n];
  }
#pragma unroll
  for (int ii = 0; ii < 4; ++ii) {
#pragma unroll
    for (int r = 0; r < 4; ++r) {
      int m = m0 + wm * 64 + ii * 16 + quad * 4 + r;
      float sxm = sx[m];
#pragma unroll
      for (int jj = 0; jj < 4; ++jj) {
        int n = n0 + wn * 64 + jj * 16 + l16;
        float v = (float)acc[ii][jj][r] * (sxm * swv[jj]) + bv[jj];
        if constexpr (MODE == 0) {
          ((__hip_bfloat16*)outp)[(size_t)m * N + n] = __float2bfloat16(v);
        } else {
          ((float*)outp)[(size_t)m * N + n] = v + resid[(size_t)m * N + n];
        }
      }
    }
  }
}

// ---------- V transpose: Vt[bh][d][k] = V[b,k,h,d] ----------
__global__ __launch_bounds__(256) void vt_kernel(
    const __hip_bfloat16* __restrict__ qkv, __hip_bfloat16* __restrict__ Vt) {
  __shared__ __hip_bfloat16 tile[64][72];
  const int bh = blockIdx.y, kc = blockIdx.x;
  const int b = bh / NH, h = bh % NH;
  const int tid = threadIdx.x;
  const size_t base = ((size_t)b * S_LEN + (size_t)kc * 64) * (3 * E_DIM) + 2 * E_DIM + h * 64;
#pragma unroll
  for (int i = 0; i < 2; ++i) {
    int idx = tid + i * 256;
    int row = idx >> 3, c8 = (idx & 7) * 8;
    *(uint4*)&tile[row][c8] = *(const uint4*)(qkv + base + (size_t)row * (3 * E_DIM) + c8);
  }
  __syncthreads();
#pragma unroll
  for (int i = 0; i < 2; ++i) {
    int idx = tid + i * 256;
    int d = idx >> 3, k8 = (idx & 7) * 8;
    __hip_bfloat16 v[8] __attribute__((aligned(16)));
#pragma unroll
    for (int j = 0; j < 8; ++j) v[j] = tile[k8 + j][d];
    *(uint4*)&Vt[((size_t)bh * 64 + d) * 1024 + (size_t)kc * 64 + k8] = *(uint4*)v;
  }
}

// ---------- flash MFMA attention: r3-exact + quarter-P (GEMM-proven swizzle) ----------
// Quarter-P v2: Ps rows are 64B (4 chunks of 16B), stored chunk = logical ^
// ((l16>>1)&3) — the exact swizzle geometry that measured 0 bank conflicts in
// the GEMM frag reads. LDS = 37.1KB -> 4 blocks/CU (16 waves/CU).
__global__ __launch_bounds__(256, 4) void attn_flash_kernel(
    const __hip_bfloat16* __restrict__ qkv, const __hip_bfloat16* __restrict__ Vt,
    __hip_bfloat16* __restrict__ attn) {
  constexpr int E3 = 3 * E_DIM;
  __shared__ __align__(16) __hip_bfloat16 Ks[128 * 64];   // [row][8 chunks, ^(row&7)]
  __shared__ __align__(16) __hip_bfloat16 Vs[64 * 128];   // [d][16 chunks, ^(d&15)]
  __shared__ __align__(16) __hip_bfloat16 Ps[4][16 * 32]; // quarter-P, 64B rows
  __shared__ float stats[4][16];

  const int tid = threadIdx.x;
  const int lane = tid & 63;
  const int wave = tid >> 6;
  const int l16 = lane & 15;
  const int quad = lane >> 4;
  const int bh = blockIdx.y;
  const int b = bh / NH, h = bh % NH;
  const int q0 = blockIdx.x * 64;
  const size_t base_t = (size_t)b * S_LEN;

  // Q B-fragments for this wave's 16 q-rows
  v8s qb0, qb1;
  {
    const __hip_bfloat16* qp =
        qkv + (base_t + q0 + wave * 16 + l16) * (size_t)E3 + h * 64 + quad * 8;
    qb0 = *(const v8s*)qp;
    qb1 = *(const v8s*)(qp + 32);
  }

  float m_prev = -3.0e38f;
  float lsum = 0.f;
  v4f oc[4];
#pragma unroll
  for (int dt = 0; dt < 4; ++dt) oc[dt] = (v4f){0.f, 0.f, 0.f, 0.f};

  const __hip_bfloat16* kgbase = qkv + base_t * E3 + E_DIM + h * 64;
  const __hip_bfloat16* vgbase = Vt + (size_t)bh * 64 * 1024;
  char* pw = (char*)Ps[wave];
  const int pswz = (l16 >> 1) & 3;               // GEMM-proven P swizzle

#pragma unroll 1
  for (int t = 0; t < 8; ++t) {
    __syncthreads();  // all waves done reading previous Ks/Vs tile
#pragma unroll
    for (int i = 0; i < 4; ++i) {   // stage K tile: 128 rows x 128B
      int c = tid + i * 256;
      int row = c >> 3, lc = c & 7;
      int gc = lc ^ (row & 7);
      gload_lds16(kgbase + (size_t)(t * 128 + row) * E3 + gc * 8, (char*)Ks + c * 16);
    }
#pragma unroll
    for (int i = 0; i < 4; ++i) {   // stage V tile: 64 d x 256B
      int c = tid + i * 256;
      int d = c >> 4, lc = c & 15;
      int gc = lc ^ (d & 15);
      gload_lds16(vgbase + (size_t)d * 1024 + t * 128 + gc * 8, (char*)Vs + c * 16);
    }
    __syncthreads();  // staged (vmcnt drained by barrier semantics)

    // ---- scores^T: D[kc][q] ; 8 kc-tiles of 16 ----
    v4f accT[8];
#pragma unroll
    for (int nt = 0; nt < 8; ++nt) {
      int row = nt * 16 + l16;
      const char* kr = (const char*)Ks + row * 128;
      v8s ak0 = *(const v8s*)(kr + ((quad ^ (row & 7)) * 16));
      v8s ak1 = *(const v8s*)(kr + (((quad + 4) ^ (row & 7)) * 16));
      v4f z = {0.f, 0.f, 0.f, 0.f};
      z = __builtin_amdgcn_mfma_f32_16x16x32_bf16(ak0, qb0, z, 0, 0, 0);
      accT[nt] = __builtin_amdgcn_mfma_f32_16x16x32_bf16(ak1, qb1, accT[nt] = z, 0, 0, 0);
    }

    // ---- online softmax (per-lane q = l16; quads hold disjoint k-slices) ----
    float mt = -3.0e38f;
#pragma unroll
    for (int nt = 0; nt < 8; ++nt)
#pragma unroll
      for (int r = 0; r < 4; ++r) mt = fmaxf(mt, accT[nt][r]);
    mt = fmaxf(mt, __shfl_xor(mt, 16, 64));
    mt = fmaxf(mt, __shfl_xor(mt, 32, 64));
    float m_new = fmaxf(m_prev, mt);
    float alpha = __expf(0.125f * (m_prev - m_new));
    m_prev = m_new;
    float ts = 0.f;
#pragma unroll
    for (int nt = 0; nt < 8; ++nt)
#pragma unroll
      for (int r = 0; r < 4; ++r) {
        float e = __expf(0.125f * (accT[nt][r] - m_new));
        accT[nt][r] = e;
        ts += e;
      }
    lsum = lsum * alpha + ts;
    if (quad == 0) stats[wave][l16] = alpha;
    // rescale O (alpha for q=quad*4+r via LDS; same-wave DS ops are in-order)
    v4f a4 = *(v4f*)&stats[wave][quad * 4];
#pragma unroll
    for (int dt = 0; dt < 4; ++dt)
#pragma unroll
      for (int r = 0; r < 4; ++r) oc[dt][r] *= a4[r];

    // ---- PV in 4 k-32 blocks; quarter-P staged per block ----
#pragma unroll
    for (int j = 0; j < 4; ++j) {
#pragma unroll
      for (int e2 = 0; e2 < 2; ++e2) {
        int nt = 2 * j + e2;
        __hip_bfloat16 pk[4] __attribute__((aligned(8)));
#pragma unroll
        for (int r = 0; r < 4; ++r) pk[r] = __float2bfloat16(accT[nt][r]);
        int lcw = 2 * e2 + (quad >> 1);
        *(uint2*)(pw + l16 * 64 + ((lcw ^ pswz) * 16) + (quad & 1) * 8) = *(uint2*)pk;
      }
      v8s ap = *(const v8s*)(pw + l16 * 64 + ((quad ^ pswz) * 16));
#pragma unroll
      for (int dt = 0; dt < 4; ++dt) {
        int d = dt * 16 + l16;
        v8s bv = *(const v8s*)((char*)Vs + d * 256 + (((j * 4 + quad) ^ l16) * 16));
        oc[dt] = __builtin_amdgcn_mfma_f32_16x16x32_bf16(ap, bv, oc[dt], 0, 0, 0);
      }
    }
  }

  // ---- epilogue: finish l, normalize, store ----
  lsum += __shfl_xor(lsum, 16, 64);
  lsum += __shfl_xor(lsum, 32, 64);
  if (quad == 0) stats[wave][l16] = lsum;
  v4f l4 = *(v4f*)&stats[wave][quad * 4];
  float inv[4];
#pragma unroll
  for (int r = 0; r < 4; ++r) inv[r] = 1.0f / l4[r];
#pragma unroll
  for (int dt = 0; dt < 4; ++dt)
#pragma unroll
    for (int r = 0; r < 4; ++r) {
      int tok = q0 + wave * 16 + quad * 4 + r;
      attn[(base_t + tok) * (size_t)E_DIM + h * 64 + dt * 16 + l16] =
          __float2bfloat16(oc[dt][r] * inv[r]);
    }
}

// ---------- launch ----------
extern "C" void kernel_launch(void* const* d_in, const int* in_sizes, int n_in,
                              void* d_out, int out_size, void* d_ws, size_t ws_size,
                              hipStream_t stream) {
  const float* hidden = (const float*)d_in[0];
  const float* ln1_w = (const float*)d_in[1];
  const float* ln1_b = (const float*)d_in[2];
  const float* ln2_w = (const float*)d_in[3];
  const float* ln2_b = (const float*)d_in[4];
  const float* W_qkv = (const float*)d_in[5];
  const float* b_qkv = (const float*)d_in[6];
  const float* W_out = (const float*)d_in[7];
  const float* b_out = (const float*)d_in[8];
  const float* W_fc1 = (const float*)d_in[9];
  const float* b_fc1 = (const float*)d_in[10];
  const float* W_fc2 = (const float*)d_in[11];
  const float* b_fc2 = (const float*)d_in[12];

  // ---- workspace plan (~250.7 MB) ----
  char* ws = (char*)d_ws;
  size_t off = 0;
  auto alloc = [&](size_t bytes) {
    void* p = ws + off;
    off += (bytes + 255) & ~(size_t)255;
    return p;
  };
  int8_t* qw_qkv = (int8_t*)alloc((size_t)3 * E_DIM * E_DIM);
  int8_t* qw_out = (int8_t*)alloc((size_t)E_DIM * E_DIM);
  int8_t* qw_fc1 = (int8_t*)alloc((size_t)F_DIM * E_DIM);
  int8_t* qw_fc2 = (int8_t*)alloc((size_t)E_DIM * F_DIM);
  float* sw_qkv = (float*)alloc((size_t)3 * E_DIM * 4);
  float* sw_out = (float*)alloc((size_t)E_DIM * 4);
  float* sw_fc1 = (float*)alloc((size_t)F_DIM * 4);
  float* sw_fc2 = (float*)alloc((size_t)E_DIM * 4);
  float* sx1 = (float*)alloc((size_t)T_DIM * 4);
  float* sa  = (float*)alloc((size_t)T_DIM * 4);
  float* sx2 = (float*)alloc((size_t)T_DIM * 4);
  float* sg  = (float*)alloc((size_t)T_DIM * 4);
  int8_t* qx = (int8_t*)alloc((size_t)T_DIM * E_DIM);              // reused 3x
  char* R = (char*)alloc((size_t)T_DIM * 3 * E_DIM * 2 +           // 209,715,200 B
                         (size_t)T_DIM * E_DIM * 4);
  __hip_bfloat16* qkv_bf = (__hip_bfloat16*)R;
  __hip_bfloat16* attn_bf = (__hip_bfloat16*)(R + (size_t)T_DIM * 3 * E_DIM * 2);
  __hip_bfloat16* Vt = (__hip_bfloat16*)(R + (size_t)T_DIM * 3 * E_DIM * 2 +
                                         (size_t)T_DIM * E_DIM * 2);
  __hip_bfloat16* f1_bf = (__hip_bfloat16*)R;
  int8_t* qg = (int8_t*)R;                                         // strided lda=2F
  float* hidden2 = (float*)d_out;

  // 1) weight quantization
  wquant_kernel<<<3 * E_DIM, 256, 0, stream>>>(W_qkv, qw_qkv, sw_qkv, E_DIM);
  wquant_kernel<<<E_DIM, 256, 0, stream>>>(W_out, qw_out, sw_out, E_DIM);
  wquant_kernel<<<F_DIM, 256, 0, stream>>>(W_fc1, qw_fc1, sw_fc1, E_DIM);
  wquant_kernel<<<E_DIM, 256, 0, stream>>>(W_fc2, qw_fc2, sw_fc2, F_DIM);
  // 2) rms1 + quant
  rms_quant_kernel<<<T_DIM, 256, 0, stream>>>(hidden, ln1_w, ln1_b, qx, sx1);
  // 3) QKV gemm -> bf16   (grid = 64 * 15 = 960 blocks)
  gemm256_i8<0><<<(T_DIM / 256) * (3 * E_DIM / 256), 512, 0, stream>>>(
      qx, qw_qkv, sx1, sw_qkv, b_qkv, nullptr, qkv_bf, T_DIM, 3 * E_DIM, E_DIM, E_DIM);
  // 4) V transpose
  vt_kernel<<<dim3(S_LEN / 64, B_SZ * NH), 256, 0, stream>>>(qkv_bf, Vt);
  // 5) flash MFMA attention -> bf16  (4 blocks/CU)
  attn_flash_kernel<<<dim3(S_LEN / 64, B_SZ * NH), 256, 0, stream>>>(qkv_bf, Vt, attn_bf);
  // 6) quant attn
  row_quant_bf_kernel<<<T_DIM, 256, 0, stream>>>(attn_bf, qx, sa);
  // 7) out proj + residual -> hidden2 (= d_out)  (grid = 128 * 10 = 1280)
  gemm128_i8<1><<<(T_DIM / 128) * (E_DIM / 128), 256, 0, stream>>>(
      qx, qw_out, sa, sw_out, b_out, hidden, hidden2, T_DIM, E_DIM, E_DIM, E_DIM);
  // 8) rms2 + quant
  rms_quant_kernel<<<T_DIM, 256, 0, stream>>>(hidden2, ln2_w, ln2_b, qx, sx2);
  // 9) FC1 gemm -> bf16   (grid = 64 * 20 = 1280)
  gemm256_i8<0><<<(T_DIM / 256) * (F_DIM / 256), 512, 0, stream>>>(
      qx, qw_fc1, sx2, sw_fc1, b_fc1, nullptr, f1_bf, T_DIM, F_DIM, E_DIM, E_DIM);
  // 10) gelu + quant (in-place strided int8 rows inside f1 buffer)
  gelu_quant_kernel<<<T_DIM, 256, 0, stream>>>(f1_bf, qg, sg);
  // 11) FC2 gemm + residual -> d_out (in-place, element-private)
  gemm128_i8<1><<<(T_DIM / 128) * (E_DIM / 128), 256, 0, stream>>>(
      qg, qw_fc2, sg, sw_fc2, b_fc2, hidden2, (float*)d_out, T_DIM, E_DIM, F_DIM, 2 * F_DIM);
}

// Round 10
// 1013.017 us; speedup vs baseline: 1.0441x; 1.0167x over previous
//
#include <hip/hip_runtime.h>
#include <hip/hip_bf16.h>
#include <stdint.h>

#define E_DIM 1280
#define F_DIM 5120
#define T_DIM 16384
#define B_SZ  16
#define S_LEN 1024
#define NH    20

typedef int v4i __attribute__((ext_vector_type(4)));
typedef __attribute__((ext_vector_type(8))) short v8s;
typedef __attribute__((ext_vector_type(4))) float v4f;

// ---------- helpers ----------
__device__ __forceinline__ float wred_sum(float v) {
#pragma unroll
  for (int m = 32; m > 0; m >>= 1) v += __shfl_xor(v, m, 64);
  return v;
}
__device__ __forceinline__ float wred_max(float v) {
#pragma unroll
  for (int m = 32; m > 0; m >>= 1) v = fmaxf(v, __shfl_xor(v, m, 64));
  return v;
}
__device__ __forceinline__ void gload_lds16(const void* g, void* l) {
  __builtin_amdgcn_global_load_lds((const __attribute__((address_space(1))) void*)g,
                                   (__attribute__((address_space(3))) void*)l, 16, 0, 0);
}

// ---------- per-output-channel weight quant ----------
__global__ __launch_bounds__(256) void wquant_kernel(
    const float* __restrict__ W, int8_t* __restrict__ qw, float* __restrict__ sw, int K) {
  __shared__ float red[4];
  const int row = blockIdx.x;
  const int tid = threadIdx.x;
  const float* wr = W + (size_t)row * K;
  float amax = 0.f;
  for (int c = tid; c < K; c += 256) amax = fmaxf(amax, fabsf(wr[c]));
  amax = wred_max(amax);
  if ((tid & 63) == 0) red[tid >> 6] = amax;
  __syncthreads();
  amax = fmaxf(fmaxf(red[0], red[1]), fmaxf(red[2], red[3]));
  float sc = amax * (1.0f / 127.0f);
  if (tid == 0) sw[row] = sc;
  for (int c = tid; c < K; c += 256) {
    float qv = rintf(wr[c] / sc);
    qw[(size_t)row * K + c] = (int8_t)qv;
  }
}

// ---------- RMSNorm(+bias) + per-token quant (E=1280) ----------
__global__ __launch_bounds__(256) void rms_quant_kernel(
    const float* __restrict__ x, const float* __restrict__ w, const float* __restrict__ b,
    int8_t* __restrict__ q, float* __restrict__ s) {
  __shared__ float red[4];
  const int row = blockIdx.x;
  const int tid = threadIdx.x;
  const float* xr = x + (size_t)row * E_DIM;
  float vals[5];
  float ss = 0.f;
#pragma unroll
  for (int i = 0; i < 5; ++i) {
    float v = xr[tid + i * 256];
    vals[i] = v; ss += v * v;
  }
  ss = wred_sum(ss);
  if ((tid & 63) == 0) red[tid >> 6] = ss;
  __syncthreads();
  ss = red[0] + red[1] + red[2] + red[3];
  float rstd = rsqrtf(ss * (1.0f / E_DIM) + 1e-6f);
  float y[5]; float amax = 0.f;
#pragma unroll
  for (int i = 0; i < 5; ++i) {
    int c = tid + i * 256;
    float v = vals[i] * rstd * w[c] + b[c];
    y[i] = v;
    amax = fmaxf(amax, fabsf(v));
  }
  amax = wred_max(amax);
  __syncthreads();
  if ((tid & 63) == 0) red[tid >> 6] = amax;
  __syncthreads();
  amax = fmaxf(fmaxf(red[0], red[1]), fmaxf(red[2], red[3]));
  float sc = amax * (1.0f / 127.0f);
  if (tid == 0) s[row] = sc;
#pragma unroll
  for (int i = 0; i < 5; ++i) {
    int c = tid + i * 256;
    float qv = rintf(y[i] / sc);
    qv = fminf(fmaxf(qv, -127.f), 127.f);
    q[(size_t)row * E_DIM + c] = (int8_t)qv;
  }
}

// ---------- per-token quant (E=1280, bf16 in) ----------
__global__ __launch_bounds__(256) void row_quant_bf_kernel(
    const __hip_bfloat16* __restrict__ x, int8_t* __restrict__ q, float* __restrict__ s) {
  __shared__ float red[4];
  const int row = blockIdx.x;
  const int tid = threadIdx.x;
  const __hip_bfloat16* xr = x + (size_t)row * E_DIM;
  float vals[5]; float amax = 0.f;
#pragma unroll
  for (int i = 0; i < 5; ++i) {
    float v = __bfloat162float(xr[tid + i * 256]);
    vals[i] = v;
    amax = fmaxf(amax, fabsf(v));
  }
  amax = wred_max(amax);
  if ((tid & 63) == 0) red[tid >> 6] = amax;
  __syncthreads();
  amax = fmaxf(fmaxf(red[0], red[1]), fmaxf(red[2], red[3]));
  float sc = amax * (1.0f / 127.0f);
  if (tid == 0) s[row] = sc;
#pragma unroll
  for (int i = 0; i < 5; ++i) {
    int c = tid + i * 256;
    float qv = rintf(vals[i] / sc);
    qv = fminf(fmaxf(qv, -127.f), 127.f);
    q[(size_t)row * E_DIM + c] = (int8_t)qv;
  }
}

// ---------- exact GELU + per-token quant (F=5120, bf16 in, int8 in-place) ----------
__global__ __launch_bounds__(256) void gelu_quant_kernel(
    const __hip_bfloat16* __restrict__ f1, int8_t* __restrict__ q, float* __restrict__ s) {
  __shared__ float red[4];
  const int row = blockIdx.x;
  const int tid = threadIdx.x;
  const __hip_bfloat16* xr = f1 + (size_t)row * F_DIM;
  float g[20]; float amax = 0.f;
#pragma unroll
  for (int i = 0; i < 20; ++i) {
    float v = __bfloat162float(xr[tid + i * 256]);
    float gv = 0.5f * v * (1.0f + erff(v * 0.70710678118654752440f));
    g[i] = gv;
    amax = fmaxf(amax, fabsf(gv));
  }
  amax = wred_max(amax);
  if ((tid & 63) == 0) red[tid >> 6] = amax;
  __syncthreads();
  amax = fmaxf(fmaxf(red[0], red[1]), fmaxf(red[2], red[3]));
  float sc = amax * (1.0f / 127.0f);
  if (tid == 0) s[row] = sc;
  int8_t* qr = q + (size_t)row * (2 * F_DIM);   // strided in-place rows
#pragma unroll
  for (int i = 0; i < 20; ++i) {
    int c = tid + i * 256;
    float qv = rintf(g[i] / sc);
    qv = fminf(fmaxf(qv, -127.f), 127.f);
    qr[c] = (int8_t)qv;
  }
}

// ============================================================================
// int8 GEMM, 256x256 tile, 8 waves, ring-of-4 K-tiles (BK=64), 16x16x64 MFMA.
// MERGED phases: one phase per K-tile {12 ds_read_b128 (af[8]+bf[4], B-frags
// read ONCE per tile), stage A+B of tile kt2+tt, barrier, 32 MFMA, vmcnt(4),
// barrier}. vs the split-half version: LDS reads -25%, barriers -50%.
// Ring/vmcnt: prologue 8 loads/thread, vmcnt(4) drains tile 0; steady state
// stages 4 loads -> 8 outstanding, vmcnt(4) retires the next tile.
// Accumulation order per acc element unchanged -> bit-identical output.
// ============================================================================
template <int MODE>
__global__ __launch_bounds__(512, 2) void gemm256_i8(
    const int8_t* __restrict__ A, const int8_t* __restrict__ B,
    const float* __restrict__ sx, const float* __restrict__ sw,
    const float* __restrict__ bias, const float* __restrict__ resid,
    void* __restrict__ outp, int M, int N, int K, int lda) {
  __shared__ __align__(16) int8_t As[2][2][256 * 64];
  __shared__ __align__(16) int8_t Bs[2][2][256 * 64];

  const int tid = threadIdx.x;
  const int lane = tid & 63;
  const int wave = tid >> 6;
  const int wm = wave >> 2;                       // 0..1  (M half)
  const int wn = wave & 3;                        // 0..3  (N quarter)
  const int l16 = lane & 15;
  const int quad = lane >> 4;
  const int choff = (quad ^ ((l16 >> 1) & 3)) << 4;   // read-side swizzled chunk

  // XCD-aware bijective swizzle (all grids divisible by 8)
  const int nwg = gridDim.x;
  const int ntn = N >> 8;
  const int u = (blockIdx.x & 7) * (nwg >> 3) + (blockIdx.x >> 3);
  const int tm = u / ntn, tn = u % ntn;
  const int m0 = tm << 8, n0 = tn << 8;

  const int8_t* A_blk = A + (size_t)m0 * lda;
  const int8_t* B_blk = B + (size_t)n0 * K;

  const int r0 = tid >> 2;                              // staged row (0..127)
  const int sch = ((tid & 3) ^ ((tid >> 3) & 3)) << 4;  // stage-side inv swizzle

#define STAGE_A(KT, DST)                                                         \
  {                                                                              \
    gload_lds16(A_blk + (size_t)r0 * lda + (size_t)(KT)*64 + sch,                \
                (DST) + tid * 16);                                               \
    gload_lds16(A_blk + (size_t)(r0 + 128) * lda + (size_t)(KT)*64 + sch,        \
                (DST) + 8192 + tid * 16);                                        \
  }
#define STAGE_B(KT, DST)                                                         \
  {                                                                              \
    gload_lds16(B_blk + (size_t)r0 * K + (size_t)(KT)*64 + sch,                  \
                (DST) + tid * 16);                                               \
    gload_lds16(B_blk + (size_t)(r0 + 128) * K + (size_t)(KT)*64 + sch,          \
                (DST) + 8192 + tid * 16);                                        \
  }

#define KTILE256(PR, TT, STAGE_STMT, WAIT_STMT)                                  \
  {                                                                              \
    const int8_t* At = &As[PR][TT][0];                                           \
    const int8_t* Bt = &Bs[PR][TT][0];                                           \
    v4i af[8], bf[4];                                                            \
    _Pragma("unroll") for (int ii = 0; ii < 8; ++ii)                             \
        af[ii] = *(const v4i*)(At + (wm * 128 + ii * 16 + l16) * 64 + choff);    \
    _Pragma("unroll") for (int jj = 0; jj < 4; ++jj)                             \
        bf[jj] = *(const v4i*)(Bt + (wn * 64 + jj * 16 + l16) * 64 + choff);     \
    STAGE_STMT;                                                                  \
    asm volatile("s_barrier" ::: "memory");                                      \
    __builtin_amdgcn_s_setprio(1);                                               \
    _Pragma("unroll") for (int ii = 0; ii < 8; ++ii)                             \
        _Pragma("unroll") for (int jj = 0; jj < 4; ++jj)                         \
            acc[ii][jj] = __builtin_amdgcn_mfma_i32_16x16x64_i8(                 \
                af[ii], bf[jj], acc[ii][jj], 0, 0, 0);                           \
    __builtin_amdgcn_s_setprio(0);                                               \
    WAIT_STMT;                                                                   \
    asm volatile("s_barrier" ::: "memory");                                      \
  }

  v4i acc[8][4];
#pragma unroll
  for (int i = 0; i < 8; ++i)
#pragma unroll
    for (int j = 0; j < 4; ++j) acc[i][j] = (v4i){0, 0, 0, 0};

  const int nk = K >> 6;          // K-tiles of 64
  const int niter = nk >> 1;      // pairs of K-tiles

  // ---- prologue: stage tiles 0,1 into pair 0; wait tile 0 (oldest 4 of 8) ----
  STAGE_A(0, &As[0][0][0]); STAGE_B(0, &Bs[0][0][0]);
  STAGE_A(1, &As[0][1][0]); STAGE_B(1, &Bs[0][1][0]);
  asm volatile("s_waitcnt vmcnt(4)" ::: "memory");
  asm volatile("s_barrier" ::: "memory");

#pragma unroll 1
  for (int i = 0; i < niter - 1; ++i) {
    const int pr = i & 1;
    const int kt2 = 2 * i + 2;
    KTILE256(pr, 0,
             { STAGE_A(kt2, &As[pr ^ 1][0][0]); STAGE_B(kt2, &Bs[pr ^ 1][0][0]); },
             asm volatile("s_waitcnt vmcnt(4)" ::: "memory"));
    KTILE256(pr, 1,
             { STAGE_A(kt2 + 1, &As[pr ^ 1][1][0]); STAGE_B(kt2 + 1, &Bs[pr ^ 1][1][0]); },
             asm volatile("s_waitcnt vmcnt(4)" ::: "memory"));
  }

  // ---- peeled final pair: no staging; drain remaining tile after tt=0 ----
  {
    const int pr = (niter - 1) & 1;
    KTILE256(pr, 0, ((void)0), asm volatile("s_waitcnt vmcnt(0)" ::: "memory"));
    KTILE256(pr, 1, ((void)0), ((void)0));
  }
#undef KTILE256
#undef STAGE_A
#undef STAGE_B

  // ---- epilogue ----
  float swv[4], bv[4];
#pragma unroll
  for (int jj = 0; jj < 4; ++jj) {
    int n = n0 + wn * 64 + jj * 16 + l16;
    swv[jj] = sw[n];
    bv[jj] = bias[n];
  }
#pragma unroll
  for (int mf = 0; mf < 8; ++mf) {
#pragma unroll
    for (int r = 0; r < 4; ++r) {
      int m = m0 + wm * 128 + mf * 16 + quad * 4 + r;
      float sxm = sx[m];
#pragma unroll
      for (int jj = 0; jj < 4; ++jj) {
        int n = n0 + wn * 64 + jj * 16 + l16;
        float v = (float)acc[mf][jj][r] * (sxm * swv[jj]) + bv[jj];
        if constexpr (MODE == 0) {
          ((__hip_bfloat16*)outp)[(size_t)m * N + n] = __float2bfloat16(v);
        } else {
          ((float*)outp)[(size_t)m * N + n] = v + resid[(size_t)m * N + n];
        }
      }
    }
  }
}

// ============================================================================
// int8 GEMM, 128x128 tile, 4 waves, ring-of-3 K-tiles, 16x16x64 MFMA.
// 48 KiB LDS -> 3 blocks/CU (12 waves/CU) for latency hiding.
// ============================================================================
template <int MODE>
__global__ __launch_bounds__(256, 3) void gemm128_i8(
    const int8_t* __restrict__ A, const int8_t* __restrict__ B,
    const float* __restrict__ sx, const float* __restrict__ sw,
    const float* __restrict__ bias, const float* __restrict__ resid,
    void* __restrict__ outp, int M, int N, int K, int lda) {
  __shared__ __align__(16) int8_t As[3][128 * 64];
  __shared__ __align__(16) int8_t Bs[3][128 * 64];

  const int tid = threadIdx.x;
  const int lane = tid & 63;
  const int wave = tid >> 6;
  const int wm = wave >> 1;                       // 0..1
  const int wn = wave & 1;                        // 0..1
  const int l16 = lane & 15;
  const int quad = lane >> 4;
  const int choff = (quad ^ ((l16 >> 1) & 3)) << 4;   // conflict-free pattern

  // XCD-aware bijective swizzle (grid divisible by 8)
  const int nwg = gridDim.x;
  const int ntn = N >> 7;
  const int u = (blockIdx.x & 7) * (nwg >> 3) + (blockIdx.x >> 3);
  const int tm = u / ntn, tn = u % ntn;
  const int m0 = tm << 7, n0 = tn << 7;

  const int8_t* A_blk = A + (size_t)m0 * lda;
  const int8_t* B_blk = B + (size_t)n0 * K;

  const int r0 = tid >> 2;                              // 0..63
  const int sch = ((tid & 3) ^ ((tid >> 3) & 3)) << 4;

#define STAGE_A(KT, SLOT)                                                        \
  {                                                                              \
    gload_lds16(A_blk + (size_t)r0 * lda + (size_t)(KT)*64 + sch,                \
                &As[SLOT][tid * 16]);                                            \
    gload_lds16(A_blk + (size_t)(r0 + 64) * lda + (size_t)(KT)*64 + sch,         \
                &As[SLOT][4096 + tid * 16]);                                     \
  }
#define STAGE_B(KT, SLOT)                                                        \
  {                                                                              \
    gload_lds16(B_blk + (size_t)r0 * K + (size_t)(KT)*64 + sch,                  \
                &Bs[SLOT][tid * 16]);                                            \
    gload_lds16(B_blk + (size_t)(r0 + 64) * K + (size_t)(KT)*64 + sch,           \
                &Bs[SLOT][4096 + tid * 16]);                                     \
  }

#define KTILE(SLOT, STAGE_STMT, WAIT_STMT)                                       \
  {                                                                              \
    const int8_t* At = &As[SLOT][0];                                             \
    const int8_t* Bt = &Bs[SLOT][0];                                             \
    v4i af[4], bf[4];                                                            \
    _Pragma("unroll") for (int ii = 0; ii < 4; ++ii)                             \
        af[ii] = *(const v4i*)(At + (wm * 64 + ii * 16 + l16) * 64 + choff);     \
    _Pragma("unroll") for (int jj = 0; jj < 4; ++jj)                             \
        bf[jj] = *(const v4i*)(Bt + (wn * 64 + jj * 16 + l16) * 64 + choff);     \
    STAGE_STMT;                                                                  \
    asm volatile("s_barrier" ::: "memory");                                      \
    __builtin_amdgcn_s_setprio(1);                                               \
    _Pragma("unroll") for (int ii = 0; ii < 4; ++ii)                             \
        _Pragma("unroll") for (int jj = 0; jj < 4; ++jj)                         \
            acc[ii][jj] = __builtin_amdgcn_mfma_i32_16x16x64_i8(                 \
                af[ii], bf[jj], acc[ii][jj], 0, 0, 0);                           \
    __builtin_amdgcn_s_setprio(0);                                               \
    WAIT_STMT;                                                                   \
    asm volatile("s_barrier" ::: "memory");                                      \
  }

  v4i acc[4][4];
#pragma unroll
  for (int i = 0; i < 4; ++i)
#pragma unroll
    for (int j = 0; j < 4; ++j) acc[i][j] = (v4i){0, 0, 0, 0};

  const int nk = K >> 6;          // >= 20 for all call sites

  // ---- prologue: stage tiles 0,1 (8 loads); wait tile 0 (oldest 4) ----
  STAGE_A(0, 0); STAGE_B(0, 0);
  STAGE_A(1, 1); STAGE_B(1, 1);
  asm volatile("s_waitcnt vmcnt(4)" ::: "memory");
  asm volatile("s_barrier" ::: "memory");

#pragma unroll 1
  for (int kt = 0; kt < nk - 2; ++kt) {
    const int sl = kt % 3;
    const int s2 = (kt + 2) % 3;
    KTILE(sl, { STAGE_A(kt + 2, s2); STAGE_B(kt + 2, s2); },
          asm volatile("s_waitcnt vmcnt(4)" ::: "memory"));
  }
  // ---- peel last 2 K-tiles (no staging; drain 4 -> 0) ----
  KTILE((nk - 2) % 3, ((void)0), asm volatile("s_waitcnt vmcnt(0)" ::: "memory"));
  KTILE((nk - 1) % 3, ((void)0), ((void)0));
#undef KTILE
#undef STAGE_A
#undef STAGE_B

  // ---- epilogue (16x16 C layout: col=lane&15, row=quad*4+r) ----
  float swv[4], bv[4];
#pragma unroll
  for (int jj = 0; jj < 4; ++jj) {
    int n = n0 + wn * 64 + jj * 16 + l16;
    swv[jj] = sw[n];
    bv[jj] = bias[n];
  }
#pragma unroll
  for (int ii = 0; ii < 4; ++ii) {
#pragma unroll
    for (int r = 0; r < 4; ++r) {
      int m = m0 + wm * 64 + ii * 16 + quad * 4 + r;
      float sxm = sx[m];
#pragma unroll
      for (int jj = 0; jj < 4; ++jj) {
        int n = n0 + wn * 64 + jj * 16 + l16;
        float v = (float)acc[ii][jj][r] * (sxm * swv[jj]) + bv[jj];
        if constexpr (MODE == 0) {
          ((__hip_bfloat16*)outp)[(size_t)m * N + n] = __float2bfloat16(v);
        } else {
          ((float*)outp)[(size_t)m * N + n] = v + resid[(size_t)m * N + n];
        }
      }
    }
  }
}

// ---------- V transpose: Vt[bh][d][k] = V[b,k,h,d] ----------
__global__ __launch_bounds__(256) void vt_kernel(
    const __hip_bfloat16* __restrict__ qkv, __hip_bfloat16* __restrict__ Vt) {
  __shared__ __hip_bfloat16 tile[64][72];
  const int bh = blockIdx.y, kc = blockIdx.x;
  const int b = bh / NH, h = bh % NH;
  const int tid = threadIdx.x;
  const size_t base = ((size_t)b * S_LEN + (size_t)kc * 64) * (3 * E_DIM) + 2 * E_DIM + h * 64;
#pragma unroll
  for (int i = 0; i < 2; ++i) {
    int idx = tid + i * 256;
    int row = idx >> 3, c8 = (idx & 7) * 8;
    *(uint4*)&tile[row][c8] = *(const uint4*)(qkv + base + (size_t)row * (3 * E_DIM) + c8);
  }
  __syncthreads();
#pragma unroll
  for (int i = 0; i < 2; ++i) {
    int idx = tid + i * 256;
    int d = idx >> 3, k8 = (idx & 7) * 8;
    __hip_bfloat16 v[8] __attribute__((aligned(16)));
#pragma unroll
    for (int j = 0; j < 8; ++j) v[j] = tile[k8 + j][d];
    *(uint4*)&Vt[((size_t)bh * 64 + d) * 1024 + (size_t)kc * 64 + k8] = *(uint4*)v;
  }
}

// ---------- flash MFMA attention: r3-exact + quarter-P (GEMM-proven swizzle) ----------
// Quarter-P v2: Ps rows are 64B (4 chunks of 16B), stored chunk = logical ^
// ((l16>>1)&3) — the exact swizzle geometry that measured 0 bank conflicts in
// the GEMM frag reads. LDS = 37.1KB -> 4 blocks/CU (16 waves/CU).
__global__ __launch_bounds__(256, 4) void attn_flash_kernel(
    const __hip_bfloat16* __restrict__ qkv, const __hip_bfloat16* __restrict__ Vt,
    __hip_bfloat16* __restrict__ attn) {
  constexpr int E3 = 3 * E_DIM;
  __shared__ __align__(16) __hip_bfloat16 Ks[128 * 64];   // [row][8 chunks, ^(row&7)]
  __shared__ __align__(16) __hip_bfloat16 Vs[64 * 128];   // [d][16 chunks, ^(d&15)]
  __shared__ __align__(16) __hip_bfloat16 Ps[4][16 * 32]; // quarter-P, 64B rows
  __shared__ float stats[4][16];

  const int tid = threadIdx.x;
  const int lane = tid & 63;
  const int wave = tid >> 6;
  const int l16 = lane & 15;
  const int quad = lane >> 4;
  const int bh = blockIdx.y;
  const int b = bh / NH, h = bh % NH;
  const int q0 = blockIdx.x * 64;
  const size_t base_t = (size_t)b * S_LEN;

  // Q B-fragments for this wave's 16 q-rows
  v8s qb0, qb1;
  {
    const __hip_bfloat16* qp =
        qkv + (base_t + q0 + wave * 16 + l16) * (size_t)E3 + h * 64 + quad * 8;
    qb0 = *(const v8s*)qp;
    qb1 = *(const v8s*)(qp + 32);
  }

  float m_prev = -3.0e38f;
  float lsum = 0.f;
  v4f oc[4];
#pragma unroll
  for (int dt = 0; dt < 4; ++dt) oc[dt] = (v4f){0.f, 0.f, 0.f, 0.f};

  const __hip_bfloat16* kgbase = qkv + base_t * E3 + E_DIM + h * 64;
  const __hip_bfloat16* vgbase = Vt + (size_t)bh * 64 * 1024;
  char* pw = (char*)Ps[wave];
  const int pswz = (l16 >> 1) & 3;               // GEMM-proven P swizzle

#pragma unroll 1
  for (int t = 0; t < 8; ++t) {
    __syncthreads();  // all waves done reading previous Ks/Vs tile
#pragma unroll
    for (int i = 0; i < 4; ++i) {   // stage K tile: 128 rows x 128B
      int c = tid + i * 256;
      int row = c >> 3, lc = c & 7;
      int gc = lc ^ (row & 7);
      gload_lds16(kgbase + (size_t)(t * 128 + row) * E3 + gc * 8, (char*)Ks + c * 16);
    }
#pragma unroll
    for (int i = 0; i < 4; ++i) {   // stage V tile: 64 d x 256B
      int c = tid + i * 256;
      int d = c >> 4, lc = c & 15;
      int gc = lc ^ (d & 15);
      gload_lds16(vgbase + (size_t)d * 1024 + t * 128 + gc * 8, (char*)Vs + c * 16);
    }
    __syncthreads();  // staged (vmcnt drained by barrier semantics)

    // ---- scores^T: D[kc][q] ; 8 kc-tiles of 16 ----
    v4f accT[8];
#pragma unroll
    for (int nt = 0; nt < 8; ++nt) {
      int row = nt * 16 + l16;
      const char* kr = (const char*)Ks + row * 128;
      v8s ak0 = *(const v8s*)(kr + ((quad ^ (row & 7)) * 16));
      v8s ak1 = *(const v8s*)(kr + (((quad + 4) ^ (row & 7)) * 16));
      v4f z = {0.f, 0.f, 0.f, 0.f};
      z = __builtin_amdgcn_mfma_f32_16x16x32_bf16(ak0, qb0, z, 0, 0, 0);
      accT[nt] = __builtin_amdgcn_mfma_f32_16x16x32_bf16(ak1, qb1, accT[nt] = z, 0, 0, 0);
    }

    // ---- online softmax (per-lane q = l16; quads hold disjoint k-slices) ----
    float mt = -3.0e38f;
#pragma unroll
    for (int nt = 0; nt < 8; ++nt)
#pragma unroll
      for (int r = 0; r < 4; ++r) mt = fmaxf(mt, accT[nt][r]);
    mt = fmaxf(mt, __shfl_xor(mt, 16, 64));
    mt = fmaxf(mt, __shfl_xor(mt, 32, 64));
    float m_new = fmaxf(m_prev, mt);
    float alpha = __expf(0.125f * (m_prev - m_new));
    m_prev = m_new;
    float ts = 0.f;
#pragma unroll
    for (int nt = 0; nt < 8; ++nt)
#pragma unroll
      for (int r = 0; r < 4; ++r) {
        float e = __expf(0.125f * (accT[nt][r] - m_new));
        accT[nt][r] = e;
        ts += e;
      }
    lsum = lsum * alpha + ts;
    if (quad == 0) stats[wave][l16] = alpha;
    // rescale O (alpha for q=quad*4+r via LDS; same-wave DS ops are in-order)
    v4f a4 = *(v4f*)&stats[wave][quad * 4];
#pragma unroll
    for (int dt = 0; dt < 4; ++dt)
#pragma unroll
      for (int r = 0; r < 4; ++r) oc[dt][r] *= a4[r];

    // ---- PV in 4 k-32 blocks; quarter-P staged per block ----
#pragma unroll
    for (int j = 0; j < 4; ++j) {
#pragma unroll
      for (int e2 = 0; e2 < 2; ++e2) {
        int nt = 2 * j + e2;
        __hip_bfloat16 pk[4] __attribute__((aligned(8)));
#pragma unroll
        for (int r = 0; r < 4; ++r) pk[r] = __float2bfloat16(accT[nt][r]);
        int lcw = 2 * e2 + (quad >> 1);
        *(uint2*)(pw + l16 * 64 + ((lcw ^ pswz) * 16) + (quad & 1) * 8) = *(uint2*)pk;
      }
      v8s ap = *(const v8s*)(pw + l16 * 64 + ((quad ^ pswz) * 16));
#pragma unroll
      for (int dt = 0; dt < 4; ++dt) {
        int d = dt * 16 + l16;
        v8s bv = *(const v8s*)((char*)Vs + d * 256 + (((j * 4 + quad) ^ l16) * 16));
        oc[dt] = __builtin_amdgcn_mfma_f32_16x16x32_bf16(ap, bv, oc[dt], 0, 0, 0);
      }
    }
  }

  // ---- epilogue: finish l, normalize, store ----
  lsum += __shfl_xor(lsum, 16, 64);
  lsum += __shfl_xor(lsum, 32, 64);
  if (quad == 0) stats[wave][l16] = lsum;
  v4f l4 = *(v4f*)&stats[wave][quad * 4];
  float inv[4];
#pragma unroll
  for (int r = 0; r < 4; ++r) inv[r] = 1.0f / l4[r];
#pragma unroll
  for (int dt = 0; dt < 4; ++dt)
#pragma unroll
    for (int r = 0; r < 4; ++r) {
      int tok = q0 + wave * 16 + quad * 4 + r;
      attn[(base_t + tok) * (size_t)E_DIM + h * 64 + dt * 16 + l16] =
          __float2bfloat16(oc[dt][r] * inv[r]);
    }
}

// ---------- launch ----------
extern "C" void kernel_launch(void* const* d_in, const int* in_sizes, int n_in,
                              void* d_out, int out_size, void* d_ws, size_t ws_size,
                              hipStream_t stream) {
  const float* hidden = (const float*)d_in[0];
  const float* ln1_w = (const float*)d_in[1];
  const float* ln1_b = (const float*)d_in[2];
  const float* ln2_w = (const float*)d_in[3];
  const float* ln2_b = (const float*)d_in[4];
  const float* W_qkv = (const float*)d_in[5];
  const float* b_qkv = (const float*)d_in[6];
  const float* W_out = (const float*)d_in[7];
  const float* b_out = (const float*)d_in[8];
  const float* W_fc1 = (const float*)d_in[9];
  const float* b_fc1 = (const float*)d_in[10];
  const float* W_fc2 = (const float*)d_in[11];
  const float* b_fc2 = (const float*)d_in[12];

  // ---- workspace plan (~250.7 MB) ----
  char* ws = (char*)d_ws;
  size_t off = 0;
  auto alloc = [&](size_t bytes) {
    void* p = ws + off;
    off += (bytes + 255) & ~(size_t)255;
    return p;
  };
  int8_t* qw_qkv = (int8_t*)alloc((size_t)3 * E_DIM * E_DIM);
  int8_t* qw_out = (int8_t*)alloc((size_t)E_DIM * E_DIM);
  int8_t* qw_fc1 = (int8_t*)alloc((size_t)F_DIM * E_DIM);
  int8_t* qw_fc2 = (int8_t*)alloc((size_t)E_DIM * F_DIM);
  float* sw_qkv = (float*)alloc((size_t)3 * E_DIM * 4);
  float* sw_out = (float*)alloc((size_t)E_DIM * 4);
  float* sw_fc1 = (float*)alloc((size_t)F_DIM * 4);
  float* sw_fc2 = (float*)alloc((size_t)E_DIM * 4);
  float* sx1 = (float*)alloc((size_t)T_DIM * 4);
  float* sa  = (float*)alloc((size_t)T_DIM * 4);
  float* sx2 = (float*)alloc((size_t)T_DIM * 4);
  float* sg  = (float*)alloc((size_t)T_DIM * 4);
  int8_t* qx = (int8_t*)alloc((size_t)T_DIM * E_DIM);              // reused 3x
  char* R = (char*)alloc((size_t)T_DIM * 3 * E_DIM * 2 +           // 209,715,200 B
                         (size_t)T_DIM * E_DIM * 4);
  __hip_bfloat16* qkv_bf = (__hip_bfloat16*)R;
  __hip_bfloat16* attn_bf = (__hip_bfloat16*)(R + (size_t)T_DIM * 3 * E_DIM * 2);
  __hip_bfloat16* Vt = (__hip_bfloat16*)(R + (size_t)T_DIM * 3 * E_DIM * 2 +
                                         (size_t)T_DIM * E_DIM * 2);
  __hip_bfloat16* f1_bf = (__hip_bfloat16*)R;
  int8_t* qg = (int8_t*)R;                                         // strided lda=2F
  float* hidden2 = (float*)d_out;

  // 1) weight quantization
  wquant_kernel<<<3 * E_DIM, 256, 0, stream>>>(W_qkv, qw_qkv, sw_qkv, E_DIM);
  wquant_kernel<<<E_DIM, 256, 0, stream>>>(W_out, qw_out, sw_out, E_DIM);
  wquant_kernel<<<F_DIM, 256, 0, stream>>>(W_fc1, qw_fc1, sw_fc1, E_DIM);
  wquant_kernel<<<E_DIM, 256, 0, stream>>>(W_fc2, qw_fc2, sw_fc2, F_DIM);
  // 2) rms1 + quant
  rms_quant_kernel<<<T_DIM, 256, 0, stream>>>(hidden, ln1_w, ln1_b, qx, sx1);
  // 3) QKV gemm -> bf16   (grid = 64 * 15 = 960 blocks)
  gemm256_i8<0><<<(T_DIM / 256) * (3 * E_DIM / 256), 512, 0, stream>>>(
      qx, qw_qkv, sx1, sw_qkv, b_qkv, nullptr, qkv_bf, T_DIM, 3 * E_DIM, E_DIM, E_DIM);
  // 4) V transpose
  vt_kernel<<<dim3(S_LEN / 64, B_SZ * NH), 256, 0, stream>>>(qkv_bf, Vt);
  // 5) flash MFMA attention -> bf16  (4 blocks/CU)
  attn_flash_kernel<<<dim3(S_LEN / 64, B_SZ * NH), 256, 0, stream>>>(qkv_bf, Vt, attn_bf);
  // 6) quant attn
  row_quant_bf_kernel<<<T_DIM, 256, 0, stream>>>(attn_bf, qx, sa);
  // 7) out proj + residual -> hidden2 (= d_out)  (grid = 128 * 10 = 1280)
  gemm128_i8<1><<<(T_DIM / 128) * (E_DIM / 128), 256, 0, stream>>>(
      qx, qw_out, sa, sw_out, b_out, hidden, hidden2, T_DIM, E_DIM, E_DIM, E_DIM);
  // 8) rms2 + quant
  rms_quant_kernel<<<T_DIM, 256, 0, stream>>>(hidden2, ln2_w, ln2_b, qx, sx2);
  // 9) FC1 gemm -> bf16   (grid = 64 * 20 = 1280)
  gemm256_i8<0><<<(T_DIM / 256) * (F_DIM / 256), 512, 0, stream>>>(
      qx, qw_fc1, sx2, sw_fc1, b_fc1, nullptr, f1_bf, T_DIM, F_DIM, E_DIM, E_DIM);
  // 10) gelu + quant (in-place strided int8 rows inside f1 buffer)
  gelu_quant_kernel<<<T_DIM, 256, 0, stream>>>(f1_bf, qg, sg);
  // 11) FC2 gemm + residual -> d_out (in-place, element-private)
  gemm128_i8<1><<<(T_DIM / 128) * (E_DIM / 128), 256, 0, stream>>>(
      qg, qw_fc2, sg, sw_fc2, b_fc2, hidden2, (float*)d_out, T_DIM, E_DIM, F_DIM, 2 * F_DIM);
}